// Round 4
// baseline (603.951 us; speedup 1.0000x reference)
//
#include <hip/hip_runtime.h>

#define N_NODES 100000
#define N_EDGES 1600000
#define F_IN 128
#define HID 64
#define NLAYERS 4
#define N_GRAPHS 512
#define N_CLASSES 10

// bucketed CSR build
#define NB_BUCKET 256
#define NODES_PER_BUCKET 391            // ceil(100000/256); 256*391 = 100096
#define NBLK 256
#define EDGES_PER_BLK (N_EDGES / NBLK)  // 6250 exactly

#define N_TILES ((N_NODES + 63) / 64)   // 1563
#define FUSED_GRID 1024                 // 4 blocks/CU x 256 CU (LDS-limited)
#define NAGG 2048                       // aggregate persistent grid

typedef unsigned int uint_t;
typedef unsigned short ushort_t;

__device__ __forceinline__ float lo_bf(uint_t w) { return __uint_as_float(w << 16); }
__device__ __forceinline__ float hi_bf(uint_t w) { return __uint_as_float(w & 0xffff0000u); }
__device__ __forceinline__ ushort_t f2bf(float f) {
    uint_t u = __float_as_uint(f);
    u += 0x7fffu + ((u >> 16) & 1u);   // round-to-nearest-even
    return (ushort_t)(u >> 16);
}
__device__ __forceinline__ uint_t pack2(float a, float b) {
    return ((uint_t)f2bf(b) << 16) | (uint_t)f2bf(a);
}

// ---------------- workspace zeroing ----------------
__global__ __launch_bounds__(256) void k_zero(int* __restrict__ btotal,
                                              float* __restrict__ statsA,
                                              float* __restrict__ pooled) {
    int i = blockIdx.x * 256 + threadIdx.x;
    if (i < NB_BUCKET) btotal[i] = 0;
    if (i < NLAYERS * 128) statsA[i] = 0.f;
    if (i < N_GRAPHS * 256) pooled[i] = 0.f;
}

// ---------------- bucketed CSR build (no global returning atomics) ----------------
__global__ __launch_bounds__(512) void kb_hist(const int* __restrict__ dst,
                                               int* __restrict__ partial,
                                               int* __restrict__ btotal) {
    __shared__ int h[NB_BUCKET];
    int tid = threadIdx.x;
    if (tid < NB_BUCKET) h[tid] = 0;
    __syncthreads();
    int e0 = blockIdx.x * EDGES_PER_BLK;
    for (int i = tid; i < EDGES_PER_BLK; i += 512) {
        uint_t d = (uint_t)dst[e0 + i];
        if (d >= (uint_t)N_NODES) d = N_NODES - 1;
        atomicAdd(&h[d / NODES_PER_BUCKET], 1);
    }
    __syncthreads();
    if (tid < NB_BUCKET) {
        int c = h[tid];
        partial[blockIdx.x * NB_BUCKET + tid] = c;
        if (c) atomicAdd(&btotal[tid], c);   // non-returning, 65K total
    }
}

__global__ __launch_bounds__(256) void kb_base(const int* __restrict__ btotal,
                                               int* __restrict__ bbase) {
    __shared__ int sh[NB_BUCKET];
    int tid = threadIdx.x;
    sh[tid] = btotal[tid];
    __syncthreads();
    for (int off = 1; off < NB_BUCKET; off <<= 1) {
        int t = (tid >= off) ? sh[tid - off] : 0;
        __syncthreads();
        sh[tid] += t;
        __syncthreads();
    }
    bbase[tid + 1] = sh[tid];
    if (tid == 0) bbase[0] = 0;
}

__global__ __launch_bounds__(256) void kb_scan(const int* __restrict__ partial,
                                               const int* __restrict__ bbase,
                                               int* __restrict__ goff) {
    __shared__ int sh[NBLK];
    int b = blockIdx.x, tid = threadIdx.x;
    sh[tid] = partial[tid * NB_BUCKET + b];
    __syncthreads();
    for (int off = 1; off < NBLK; off <<= 1) {
        int t = (tid >= off) ? sh[tid - off] : 0;
        __syncthreads();
        sh[tid] += t;
        __syncthreads();
    }
    int excl = (tid == 0) ? 0 : sh[tid - 1];
    goff[tid * NB_BUCKET + b] = bbase[b] + excl;
}

__global__ __launch_bounds__(512) void kb_scatter(const int* __restrict__ src,
                                                  const int* __restrict__ dst,
                                                  const int* __restrict__ goff,
                                                  int* __restrict__ ebuf) {
    __shared__ int cur[NB_BUCKET];
    int tid = threadIdx.x;
    if (tid < NB_BUCKET) cur[tid] = goff[blockIdx.x * NB_BUCKET + tid];
    __syncthreads();
    int e0 = blockIdx.x * EDGES_PER_BLK;
    for (int i = tid; i < EDGES_PER_BLK; i += 512) {
        uint_t d = (uint_t)dst[e0 + i];
        if (d >= (uint_t)N_NODES) d = N_NODES - 1;
        uint_t s = (uint_t)src[e0 + i];
        if (s >= (uint_t)N_NODES) s = 0;
        int b = (int)(d / NODES_PER_BUCKET);
        int dl = (int)d - b * NODES_PER_BUCKET;     // < 391, 9 bits
        int pos = atomicAdd(&cur[b], 1);            // LDS returning atomic
        ebuf[pos] = (dl << 17) | (int)s;            // src < 2^17
    }
}

__global__ __launch_bounds__(512) void kb_csr(const int* __restrict__ ebuf,
                                              const int* __restrict__ bbase,
                                              int* __restrict__ row_ptr,
                                              int* __restrict__ col_src) {
    __shared__ int cnt[512];
    __shared__ int sh[512];
    __shared__ int off[512];
    int tid = threadIdx.x, b = blockIdx.x;
    int s0 = bbase[b], s1 = bbase[b + 1];
    int n = s1 - s0;
    cnt[tid] = 0;
    __syncthreads();
    for (int i = tid; i < n; i += 512) {
        int dl = ebuf[s0 + i] >> 17;
        atomicAdd(&cnt[dl], 1);
    }
    __syncthreads();
    sh[tid] = cnt[tid];
    __syncthreads();
    for (int o = 1; o < 512; o <<= 1) {
        int t = (tid >= o) ? sh[tid - o] : 0;
        __syncthreads();
        sh[tid] += t;
        __syncthreads();
    }
    off[tid] = (tid == 0) ? 0 : sh[tid - 1];
    cnt[tid] = 0;

    int node0 = b * NODES_PER_BUCKET;
    int ncnt = N_NODES - node0;
    if (ncnt > NODES_PER_BUCKET) ncnt = NODES_PER_BUCKET;
    if (tid < ncnt) row_ptr[node0 + tid] = s0 + off[tid];
    if (b == NB_BUCKET - 1 && tid == 0) row_ptr[N_NODES] = N_EDGES;
    __syncthreads();

    for (int i = tid; i < n; i += 512) {
        int v = ebuf[s0 + i];
        int dl = v >> 17;
        int r = atomicAdd(&cnt[dl], 1);             // LDS returning atomic
        col_src[s0 + off[dl] + r] = v & 0x1FFFF;
    }
}

// ---------------- aggregation on bf16 y (dim 64) -> bf16 u, fused column stats ----------------
__global__ __launch_bounds__(256) void k_aggregate_u(const uint2* __restrict__ y2,
                                                     const int* __restrict__ row_ptr,
                                                     const int* __restrict__ col_src,
                                                     const float* __restrict__ eps, int layer,
                                                     const float* __restrict__ b1,
                                                     uint2* __restrict__ u2,
                                                     float* __restrict__ partialsT) {
    __shared__ float red[512];   // [4 waves][16 l4][8: sum4,sq4]
    int tid = threadIdx.x;
    int wid = tid >> 6, lane = tid & 63;
    int gid = lane >> 4, l4 = lane & 15;
    float one_eps = 1.0f + eps[layer];
    int stride = gridDim.x * 4;

    float4 ss = {0.f, 0.f, 0.f, 0.f};   // column sums (only gid==0 lanes)
    float4 sq = {0.f, 0.f, 0.f, 0.f};   // column sum-of-squares

    for (int node = blockIdx.x * 4 + wid; node < N_NODES; node += stride) {
        int e0 = row_ptr[node], e1 = row_ptr[node + 1];
        if (e0 < 0) e0 = 0;
        if (e1 > N_EDGES) e1 = N_EDGES;
        if (e1 < e0) e1 = e0;

        float4 a0 = {0.f, 0.f, 0.f, 0.f}, a1 = a0, a2 = a0, a3 = a0;

        for (int ebase = e0; ebase < e1; ebase += 64) {
            int len = e1 - ebase; if (len > 64) len = 64;
            int ci = ebase + lane; if (ci > e1 - 1) ci = e1 - 1;
            int sv = col_src[ci];
            sv = (int)min((uint_t)sv, (uint_t)(N_NODES - 1));

            int nfull = len >> 2;
            int rem = len & 3;
            int j = 0;
            for (; j + 4 <= nfull; j += 4) {
                int s0 = __shfl(sv, (j + 0) * 4 + gid, 64);
                int s1 = __shfl(sv, (j + 1) * 4 + gid, 64);
                int s2 = __shfl(sv, (j + 2) * 4 + gid, 64);
                int s3 = __shfl(sv, (j + 3) * 4 + gid, 64);
                uint2 w0 = y2[(size_t)s0 * 16 + l4];
                uint2 w1 = y2[(size_t)s1 * 16 + l4];
                uint2 w2 = y2[(size_t)s2 * 16 + l4];
                uint2 w3 = y2[(size_t)s3 * 16 + l4];
                a0.x += lo_bf(w0.x); a0.y += hi_bf(w0.x); a0.z += lo_bf(w0.y); a0.w += hi_bf(w0.y);
                a1.x += lo_bf(w1.x); a1.y += hi_bf(w1.x); a1.z += lo_bf(w1.y); a1.w += hi_bf(w1.y);
                a2.x += lo_bf(w2.x); a2.y += hi_bf(w2.x); a2.z += lo_bf(w2.y); a2.w += hi_bf(w2.y);
                a3.x += lo_bf(w3.x); a3.y += hi_bf(w3.x); a3.z += lo_bf(w3.y); a3.w += hi_bf(w3.y);
            }
            for (; j < nfull; ++j) {
                int s = __shfl(sv, j * 4 + gid, 64);
                uint2 w = y2[(size_t)s * 16 + l4];
                a0.x += lo_bf(w.x); a0.y += hi_bf(w.x); a0.z += lo_bf(w.y); a0.w += hi_bf(w.y);
            }
            if (rem) {
                int s = __shfl(sv, nfull * 4 + gid, 64);
                if (gid < rem) {
                    uint2 w = y2[(size_t)s * 16 + l4];
                    a1.x += lo_bf(w.x); a1.y += hi_bf(w.x); a1.z += lo_bf(w.y); a1.w += hi_bf(w.y);
                }
            }
        }

        float4 t;
        t.x = (a0.x + a1.x) + (a2.x + a3.x);
        t.y = (a0.y + a1.y) + (a2.y + a3.y);
        t.z = (a0.z + a1.z) + (a2.z + a3.z);
        t.w = (a0.w + a1.w) + (a2.w + a3.w);
        t.x += __shfl_xor(t.x, 16, 64); t.x += __shfl_xor(t.x, 32, 64);
        t.y += __shfl_xor(t.y, 16, 64); t.y += __shfl_xor(t.y, 32, 64);
        t.z += __shfl_xor(t.z, 16, 64); t.z += __shfl_xor(t.z, 32, 64);
        t.w += __shfl_xor(t.w, 16, 64); t.w += __shfl_xor(t.w, 32, 64);

        if (gid == 0) {
            uint2 ws = y2[(size_t)node * 16 + l4];
            float4 bb = *(const float4*)&b1[4 * l4];
            float ox = t.x + one_eps * lo_bf(ws.x) + bb.x;
            float oy = t.y + one_eps * hi_bf(ws.x) + bb.y;
            float oz = t.z + one_eps * lo_bf(ws.y) + bb.z;
            float ow = t.w + one_eps * hi_bf(ws.y) + bb.w;
            uint2 o2;
            o2.x = pack2(ox, oy);
            o2.y = pack2(oz, ow);
            u2[(size_t)node * 16 + l4] = o2;
            // stats from the packed (bf16-rounded) values — matches old k_stats
            float q0 = lo_bf(o2.x), q1 = hi_bf(o2.x), q2 = lo_bf(o2.y), q3 = hi_bf(o2.y);
            ss.x += q0; ss.y += q1; ss.z += q2; ss.w += q3;
            sq.x += q0 * q0; sq.y += q1 * q1; sq.z += q2 * q2; sq.w += q3 * q3;
        }
    }

    // block reduce of column stats -> one write per block (no atomics)
    if (gid == 0) {
        int off = (wid * 16 + l4) * 8;
        red[off + 0] = ss.x; red[off + 1] = ss.y; red[off + 2] = ss.z; red[off + 3] = ss.w;
        red[off + 4] = sq.x; red[off + 5] = sq.y; red[off + 6] = sq.z; red[off + 7] = sq.w;
    }
    __syncthreads();
    if (tid < 128) {
        int sel = tid >> 6, c = tid & 63;
        int l4i = c >> 2, j = c & 3;
        float v = red[(0 * 16 + l4i) * 8 + sel * 4 + j]
                + red[(1 * 16 + l4i) * 8 + sel * 4 + j]
                + red[(2 * 16 + l4i) * 8 + sel * 4 + j]
                + red[(3 * 16 + l4i) * 8 + sel * 4 + j];
        partialsT[(size_t)(sel * 64 + c) * NAGG + blockIdx.x] = v;
    }
}

// reduce transposed partials [128][NAGG] -> statsA layer slice [128]
__global__ __launch_bounds__(256) void k_redstats(const float* __restrict__ pT,
                                                  float* __restrict__ outp) {
    __shared__ float sh[256];
    int b = blockIdx.x, tid = threadIdx.x;
    float v = 0.f;
    for (int i = tid; i < NAGG; i += 256) v += pT[(size_t)b * NAGG + i];
    sh[tid] = v;
    __syncthreads();
    for (int off = 128; off > 0; off >>= 1) {
        if (tid < off) sh[tid] += sh[tid + off];
        __syncthreads();
    }
    if (tid == 0) outp[b] = sh[0];
}

// ---------------- GEMM1 (layer 0 only): ybf = bf16(x @ W1_0) ----------------
template <int K>
__global__ __launch_bounds__(256) void k_gemm1(const float* __restrict__ A,
                                               const float* __restrict__ W,
                                               ushort_t* __restrict__ out) {
    constexpr int KP = K + 4;
    constexpr int KQ = K / 4;
    __shared__ float Al[64 * KP];
    __shared__ float Wl[K * 64];
    int tid = threadIdx.x;
    int base = blockIdx.x * 64;

    for (int i = tid; i < K * 16; i += 256)
        ((float4*)Wl)[i] = ((const float4*)W)[i];

    if (base + 64 <= N_NODES) {
        const float4* Ag = (const float4*)(A + (size_t)base * K);
        for (int i = tid; i < 16 * K; i += 256) {
            int row = i / KQ, kk = (i % KQ) * 4;
            float4 v = Ag[i];
            *(float4*)&Al[row * KP + kk] = v;
        }
    } else {
        for (int i = tid; i < 16 * K; i += 256) {
            int row = i / KQ, kk = (i % KQ) * 4;
            int grow = base + row; if (grow >= N_NODES) grow = N_NODES - 1;
            float4 v = ((const float4*)(A + (size_t)grow * K))[i % KQ];
            *(float4*)&Al[row * KP + kk] = v;
        }
    }
    __syncthreads();

    int ct = (tid & 15) * 4;
    int rb = (tid >> 4) * 4;
    float4 acc0 = {0.f, 0.f, 0.f, 0.f}, acc1 = acc0, acc2 = acc0, acc3 = acc0;
    const float* A0 = &Al[(rb + 0) * KP];
    const float* A1 = &Al[(rb + 1) * KP];
    const float* A2 = &Al[(rb + 2) * KP];
    const float* A3 = &Al[(rb + 3) * KP];
    #pragma unroll 4
    for (int k = 0; k < K; ++k) {
        float4 w = *(const float4*)&Wl[k * 64 + ct];
        float a0 = A0[k], a1 = A1[k], a2 = A2[k], a3 = A3[k];
        acc0.x = fmaf(a0, w.x, acc0.x); acc0.y = fmaf(a0, w.y, acc0.y);
        acc0.z = fmaf(a0, w.z, acc0.z); acc0.w = fmaf(a0, w.w, acc0.w);
        acc1.x = fmaf(a1, w.x, acc1.x); acc1.y = fmaf(a1, w.y, acc1.y);
        acc1.z = fmaf(a1, w.z, acc1.z); acc1.w = fmaf(a1, w.w, acc1.w);
        acc2.x = fmaf(a2, w.x, acc2.x); acc2.y = fmaf(a2, w.y, acc2.y);
        acc2.z = fmaf(a2, w.z, acc2.z); acc2.w = fmaf(a2, w.w, acc2.w);
        acc3.x = fmaf(a3, w.x, acc3.x); acc3.y = fmaf(a3, w.y, acc3.y);
        acc3.z = fmaf(a3, w.z, acc3.z); acc3.w = fmaf(a3, w.w, acc3.w);
    }

    float4 accs[4] = {acc0, acc1, acc2, acc3};
    #pragma unroll
    for (int r = 0; r < 4; ++r) {
        int row = base + rb + r;
        if (row < N_NODES) {
            ushort4 o;
            o.x = f2bf(accs[r].x); o.y = f2bf(accs[r].y);
            o.z = f2bf(accs[r].z); o.w = f2bf(accs[r].w);
            *(ushort4*)&out[(size_t)row * 64 + ct] = o;
        }
    }
}

// ---------------- fused layer tail (bf16 u input), persistent, shared weight buffer ----------------
template <bool NEXT>
__global__ __launch_bounds__(256) void k_fused(const uint2* __restrict__ U2,
                                               const float* __restrict__ W2,
                                               const float* __restrict__ sums,
                                               const float* __restrict__ g_,
                                               const float* __restrict__ be,
                                               const float* __restrict__ b2,
                                               const int* __restrict__ batch,
                                               float* __restrict__ pooled, int layer,
                                               const float* __restrict__ W1n,
                                               ushort_t* __restrict__ ynext) {
    constexpr int K = 64, KP = 68, KQ = 16;
    __shared__ float Al[64 * KP];       // 17408 B
    __shared__ float Wl[K * 64];        // 16384 B (time-shared: W2 then W1n)
    __shared__ float Pl[256];
    __shared__ __align__(16) float Sc[64];
    __shared__ __align__(16) float Sh[64];
    int tid = threadIdx.x;

    if (tid < 64) {
        const float inv_n = 1.0f / N_NODES;
        float mean = sums[tid] * inv_n;
        float var = sums[64 + tid] * inv_n - mean * mean;
        if (var < 0.f) var = 0.f;
        float inv = rsqrtf(var + 1e-5f);
        float sc = inv * g_[tid];
        Sc[tid] = sc;
        Sh[tid] = be[tid] - mean * sc;
    }
    __syncthreads();

    int ct = (tid & 15) * 4;
    int rb = (tid >> 4) * 4;

    for (int tile = blockIdx.x; tile < N_TILES; tile += gridDim.x) {
        int base = tile * 64;

        // load Wl <- W2 ; build Al = relu(BN(u))
        for (int i = tid; i < K * 16; i += 256)
            ((float4*)Wl)[i] = ((const float4*)W2)[i];
        {
            bool full = (base + 64 <= N_NODES);
            for (int i = tid; i < 16 * K; i += 256) {
                int row = i / KQ, kq = i % KQ, kk = kq * 4;
                int grow = base + row;
                if (!full && grow >= N_NODES) grow = N_NODES - 1;
                uint2 w = U2[(size_t)grow * 16 + kq];
                float4 v = {lo_bf(w.x), hi_bf(w.x), lo_bf(w.y), hi_bf(w.y)};
                float4 sc = *(const float4*)&Sc[kk];
                float4 sh = *(const float4*)&Sh[kk];
                v.x = fmaxf(fmaf(v.x, sc.x, sh.x), 0.f);
                v.y = fmaxf(fmaf(v.y, sc.y, sh.y), 0.f);
                v.z = fmaxf(fmaf(v.z, sc.z, sh.z), 0.f);
                v.w = fmaxf(fmaf(v.w, sc.w, sh.w), 0.f);
                *(float4*)&Al[row * KP + kk] = v;
            }
        }
        __syncthreads();

        // GEMM1: h = Al(u) @ Wl(W2)
        float4 acc0 = {0.f, 0.f, 0.f, 0.f}, acc1 = acc0, acc2 = acc0, acc3 = acc0;
        {
            const float* A0 = &Al[(rb + 0) * KP];
            const float* A1 = &Al[(rb + 1) * KP];
            const float* A2 = &Al[(rb + 2) * KP];
            const float* A3 = &Al[(rb + 3) * KP];
            #pragma unroll 4
            for (int k = 0; k < K; ++k) {
                float4 w = *(const float4*)&Wl[k * 64 + ct];
                float a0 = A0[k], a1 = A1[k], a2 = A2[k], a3 = A3[k];
                acc0.x = fmaf(a0, w.x, acc0.x); acc0.y = fmaf(a0, w.y, acc0.y);
                acc0.z = fmaf(a0, w.z, acc0.z); acc0.w = fmaf(a0, w.w, acc0.w);
                acc1.x = fmaf(a1, w.x, acc1.x); acc1.y = fmaf(a1, w.y, acc1.y);
                acc1.z = fmaf(a1, w.z, acc1.z); acc1.w = fmaf(a1, w.w, acc1.w);
                acc2.x = fmaf(a2, w.x, acc2.x); acc2.y = fmaf(a2, w.y, acc2.y);
                acc2.z = fmaf(a2, w.z, acc2.z); acc2.w = fmaf(a2, w.w, acc2.w);
                acc3.x = fmaf(a3, w.x, acc3.x); acc3.y = fmaf(a3, w.y, acc3.y);
                acc3.z = fmaf(a3, w.z, acc3.z); acc3.w = fmaf(a3, w.w, acc3.w);
            }
        }
        __syncthreads();   // done reading Al(u) and Wl(W2)

        // write h into Al; load Wl <- W1n (different buffers, both writes)
        {
            float4 bb = *(const float4*)&b2[ct];
            float4 accs[4] = {acc0, acc1, acc2, acc3};
            #pragma unroll
            for (int r = 0; r < 4; ++r) {
                float4 o;
                o.x = fmaxf(accs[r].x + bb.x, 0.f);
                o.y = fmaxf(accs[r].y + bb.y, 0.f);
                o.z = fmaxf(accs[r].z + bb.z, 0.f);
                o.w = fmaxf(accs[r].w + bb.w, 0.f);
                *(float4*)&Al[(rb + r) * KP + ct] = o;
            }
        }
        if (NEXT) {
            for (int i = tid; i < K * 16; i += 256)
                ((float4*)Wl)[i] = ((const float4*)W1n)[i];
        }
        __syncthreads();   // h tile + W1n ready

        // GEMM2 first (no internal barriers): ynext = bf16(h @ W1n)
        if (NEXT) {
            float4 y0 = {0.f, 0.f, 0.f, 0.f}, y1 = y0, y2_ = y0, y3 = y0;
            const float* A0 = &Al[(rb + 0) * KP];
            const float* A1 = &Al[(rb + 1) * KP];
            const float* A2 = &Al[(rb + 2) * KP];
            const float* A3 = &Al[(rb + 3) * KP];
            #pragma unroll 4
            for (int k = 0; k < K; ++k) {
                float4 w = *(const float4*)&Wl[k * 64 + ct];
                float a0 = A0[k], a1 = A1[k], a2 = A2[k], a3 = A3[k];
                y0.x = fmaf(a0, w.x, y0.x); y0.y = fmaf(a0, w.y, y0.y);
                y0.z = fmaf(a0, w.z, y0.z); y0.w = fmaf(a0, w.w, y0.w);
                y1.x = fmaf(a1, w.x, y1.x); y1.y = fmaf(a1, w.y, y1.y);
                y1.z = fmaf(a1, w.z, y1.z); y1.w = fmaf(a1, w.w, y1.w);
                y2_.x = fmaf(a2, w.x, y2_.x); y2_.y = fmaf(a2, w.y, y2_.y);
                y2_.z = fmaf(a2, w.z, y2_.z); y2_.w = fmaf(a2, w.w, y2_.w);
                y3.x = fmaf(a3, w.x, y3.x); y3.y = fmaf(a3, w.y, y3.y);
                y3.z = fmaf(a3, w.z, y3.z); y3.w = fmaf(a3, w.w, y3.w);
            }
            float4 ys[4] = {y0, y1, y2_, y3};
            #pragma unroll
            for (int r = 0; r < 4; ++r) {
                int row = base + rb + r;
                if (row < N_NODES) {
                    ushort4 o;
                    o.x = f2bf(ys[r].x); o.y = f2bf(ys[r].y);
                    o.z = f2bf(ys[r].z); o.w = f2bf(ys[r].w);
                    *(ushort4*)&ynext[(size_t)row * 64 + ct] = o;
                }
            }
        }

        // pooling over graph segments (batch sorted); internal barriers
        {
            int lastEx = base + 64; if (lastEx > N_NODES) lastEx = N_NODES;
            int gstart = batch[base];
            int gend = batch[lastEx - 1];
            if (gstart < 0) gstart = 0;
            if (gend > N_GRAPHS - 1) gend = N_GRAPHS - 1;
            int col = tid & 63, q = tid >> 6;
            int rs = base;
            for (int g = gstart; g <= gend; ++g) {
                int lo = rs, hi = lastEx;
                while (lo < hi) { int mid = (lo + hi) >> 1; if (batch[mid] <= g) lo = mid + 1; else hi = mid; }
                int re = lo;
                float s = 0.f;
                for (int r = rs + q; r < re; r += 4) s += Al[(r - base) * KP + col];
                Pl[tid] = s;
                __syncthreads();
                if (tid < 64) {
                    float tot = (Pl[col] + Pl[64 + col]) + (Pl[128 + col] + Pl[192 + col]);
                    atomicAdd(&pooled[g * 256 + layer * 64 + col], tot);
                }
                __syncthreads();
                rs = re;
            }
        }
        __syncthreads();   // tile end: Al/Wl safe to overwrite
    }
}

// ---------------- head ----------------
__global__ __launch_bounds__(64) void k_head1(const float* __restrict__ pooled,
                                              const float* __restrict__ W, const float* __restrict__ b,
                                              float* __restrict__ t1) {
    __shared__ __align__(16) float pl[256];
    int g = blockIdx.x, lane = threadIdx.x;
    ((float4*)pl)[lane] = ((const float4*)(pooled + g * 256))[lane];
    __syncthreads();
    float acc = b[lane];
    for (int k = 0; k < 256; ++k) acc += pl[k] * W[k * 64 + lane];
    t1[g * 64 + lane] = acc;
}

__global__ __launch_bounds__(64) void k_head3(const float* __restrict__ t1,
                                              const float* __restrict__ g_, const float* __restrict__ b_,
                                              const float* __restrict__ W2, const float* __restrict__ b2,
                                              float* __restrict__ out) {
    __shared__ float v[64];
    __shared__ float o[16];
    int g = blockIdx.x, lane = threadIdx.x;
    float s = 0.f, q = 0.f;
    for (int r = 0; r < N_GRAPHS; ++r) {
        float vv = t1[r * 64 + lane];
        s += vv; q += vv * vv;
    }
    float mean = s * (1.0f / N_GRAPHS);
    float var = q * (1.0f / N_GRAPHS) - mean * mean;
    if (var < 0.f) var = 0.f;
    float inv = rsqrtf(var + 1e-5f);
    float sc = inv * g_[lane];
    float sh = b_[lane] - mean * sc;
    float x = t1[g * 64 + lane] * sc + sh;
    v[lane] = fmaxf(x, 0.f);
    __syncthreads();
    if (lane < N_CLASSES) {
        float acc = b2[lane];
        for (int k = 0; k < 64; ++k) acc += v[k] * W2[k * N_CLASSES + lane];
        o[lane] = acc;
    }
    __syncthreads();
    if (lane < N_CLASSES) {
        float m = -1e30f;
        for (int k = 0; k < N_CLASSES; ++k) m = fmaxf(m, o[k]);
        float ssum = 0.f;
        for (int k = 0; k < N_CLASSES; ++k) ssum += expf(o[k] - m);
        out[g * N_CLASSES + lane] = o[lane] - m - logf(ssum);
    }
}

// ---------------- launch ----------------
extern "C" void kernel_launch(void* const* d_in, const int* in_sizes, int n_in,
                              void* d_out, int out_size, void* d_ws, size_t ws_size,
                              hipStream_t stream) {
    const float* x      = (const float*)d_in[0];
    const int*   ei     = (const int*)d_in[1];
    const int*   srcArr = ei;
    const int*   dstArr = ei + N_EDGES;
    const int*   batch  = (const int*)d_in[2];
    const float* eps    = (const float*)d_in[3];
    const float* W1_0   = (const float*)d_in[4];
    const float* b1_0   = (const float*)d_in[5];
    const float* g_0    = (const float*)d_in[6];
    const float* be_0   = (const float*)d_in[7];
    const float* W2_0   = (const float*)d_in[8];
    const float* b2_0   = (const float*)d_in[9];
    const float* W1_r   = (const float*)d_in[10];
    const float* b1_r   = (const float*)d_in[11];
    const float* g_r    = (const float*)d_in[12];
    const float* be_r   = (const float*)d_in[13];
    const float* W2_r   = (const float*)d_in[14];
    const float* b2_r   = (const float*)d_in[15];
    const float* lin1W  = (const float*)d_in[16];
    const float* lin1b  = (const float*)d_in[17];
    const float* bn_g   = (const float*)d_in[18];
    const float* bn_b   = (const float*)d_in[19];
    const float* lin2W  = (const float*)d_in[20];
    const float* lin2b  = (const float*)d_in[21];

    char* ws = (char*)d_ws;
    auto alloc = [&](size_t bytes) {
        char* p = ws;
        ws += (bytes + 255) & ~(size_t)255;
        return p;
    };
    int*      row_ptr  = (int*)alloc(((size_t)N_NODES + 1) * 4);
    int*      col_src  = (int*)alloc((size_t)N_EDGES * 4);
    int*      ebuf     = (int*)alloc((size_t)N_EDGES * 4);
    int*      partial  = (int*)alloc((size_t)NBLK * NB_BUCKET * 4);
    int*      goff     = (int*)alloc((size_t)NBLK * NB_BUCKET * 4);
    int*      btotal   = (int*)alloc((size_t)NB_BUCKET * 4);
    int*      bbase    = (int*)alloc(((size_t)NB_BUCKET + 1) * 4);
    ushort_t* ybf      = (ushort_t*)alloc((size_t)N_NODES * 64 * 2);
    ushort_t* ubf      = (ushort_t*)alloc((size_t)N_NODES * 64 * 2);
    float*    statsA   = (float*)alloc(NLAYERS * 128 * 4);
    float*    pooled   = (float*)alloc((size_t)N_GRAPHS * 256 * 4);
    float*    t1       = (float*)alloc((size_t)N_GRAPHS * 64 * 4);
    // partialsT aliases ebuf: ebuf is dead after kb_csr; partialsT is
    // written only by k_aggregate_u (stream-ordered after kb_csr).
    // 128 * NAGG * 4 = 1 MB <= 6.4 MB. Keeps workspace at the R2 footprint.
    float*    partialsT = (float*)ebuf;

    k_zero<<<(N_GRAPHS * 256 + 255) / 256, 256, 0, stream>>>(btotal, statsA, pooled);
    kb_hist<<<NBLK, 512, 0, stream>>>(dstArr, partial, btotal);
    kb_base<<<1, 256, 0, stream>>>(btotal, bbase);
    kb_scan<<<NB_BUCKET, 256, 0, stream>>>(partial, bbase, goff);
    kb_scatter<<<NBLK, 512, 0, stream>>>(srcArr, dstArr, goff, ebuf);
    kb_csr<<<NB_BUCKET, 512, 0, stream>>>(ebuf, bbase, row_ptr, col_src);

    const int gemm_grid = (N_NODES + 63) / 64;      // 1563

    // layer 0 front GEMM: y0 = bf16(x @ W1_0)
    k_gemm1<128><<<gemm_grid, 256, 0, stream>>>(x, W1_0, ybf);

    for (int l = 0; l < NLAYERS; ++l) {
        const float *b1, *gg, *be, *W2, *b2;
        if (l == 0) { b1 = b1_0; gg = g_0; be = be_0; W2 = W2_0; b2 = b2_0; }
        else {
            b1 = b1_r + (size_t)(l - 1) * 64;
            gg = g_r  + (size_t)(l - 1) * 64;
            be = be_r + (size_t)(l - 1) * 64;
            W2 = W2_r + (size_t)(l - 1) * 64 * 64;
            b2 = b2_r + (size_t)(l - 1) * 64;
        }
        k_aggregate_u<<<NAGG, 256, 0, stream>>>((const uint2*)ybf, row_ptr, col_src, eps, l, b1,
                                                (uint2*)ubf, partialsT);
        k_redstats<<<128, 256, 0, stream>>>(partialsT, statsA + l * 128);
        if (l < NLAYERS - 1) {
            const float* W1n = W1_r + (size_t)l * 64 * 64;
            k_fused<true><<<FUSED_GRID, 256, 0, stream>>>((const uint2*)ubf, W2, statsA + l * 128, gg, be, b2,
                                                          batch, pooled, l, W1n, ybf);
        } else {
            k_fused<false><<<FUSED_GRID, 256, 0, stream>>>((const uint2*)ubf, W2, statsA + l * 128, gg, be, b2,
                                                           batch, pooled, l, nullptr, nullptr);
        }
    }

    k_head1<<<N_GRAPHS, 64, 0, stream>>>(pooled, lin1W, lin1b, t1);
    k_head3<<<N_GRAPHS, 64, 0, stream>>>(t1, bn_g, bn_b, lin2W, lin2b, (float*)d_out);
}

// Round 5
// 550.805 us; speedup vs baseline: 1.0965x; 1.0965x over previous
//
#include <hip/hip_runtime.h>

#define N_NODES 100000
#define N_EDGES 1600000
#define F_IN 128
#define HID 64
#define NLAYERS 4
#define N_GRAPHS 512
#define N_CLASSES 10

// bucketed CSR build
#define NB_BUCKET 256
#define NODES_PER_BUCKET 391            // ceil(100000/256); 256*391 = 100096
#define NBLK 256
#define EDGES_PER_BLK (N_EDGES / NBLK)  // 6250 exactly

#define N_TILES ((N_NODES + 63) / 64)   // 1563
#define FUSED_GRID 1024                 // 4 blocks/CU x 256 CU (LDS-limited)
#define NAGG 2048                       // aggregate persistent grid

typedef unsigned int uint_t;
typedef unsigned short ushort_t;

__device__ __forceinline__ float lo_bf(uint_t w) { return __uint_as_float(w << 16); }
__device__ __forceinline__ float hi_bf(uint_t w) { return __uint_as_float(w & 0xffff0000u); }
__device__ __forceinline__ ushort_t f2bf(float f) {
    uint_t u = __float_as_uint(f);
    u += 0x7fffu + ((u >> 16) & 1u);   // round-to-nearest-even
    return (ushort_t)(u >> 16);
}
__device__ __forceinline__ uint_t pack2(float a, float b) {
    return ((uint_t)f2bf(b) << 16) | (uint_t)f2bf(a);
}

// ---------------- workspace zeroing ----------------
__global__ __launch_bounds__(256) void k_zero(int* __restrict__ btotal,
                                              float* __restrict__ statsA,
                                              float* __restrict__ pooled) {
    int i = blockIdx.x * 256 + threadIdx.x;
    if (i < NB_BUCKET) btotal[i] = 0;
    if (i < NLAYERS * 128) statsA[i] = 0.f;
    if (i < N_GRAPHS * 256) pooled[i] = 0.f;
}

// ---------------- bucketed CSR build (no global returning atomics) ----------------
__global__ __launch_bounds__(512) void kb_hist(const int* __restrict__ dst,
                                               int* __restrict__ partial,
                                               int* __restrict__ btotal) {
    __shared__ int h[NB_BUCKET];
    int tid = threadIdx.x;
    if (tid < NB_BUCKET) h[tid] = 0;
    __syncthreads();
    int e0 = blockIdx.x * EDGES_PER_BLK;
    for (int i = tid; i < EDGES_PER_BLK; i += 512) {
        uint_t d = (uint_t)dst[e0 + i];
        if (d >= (uint_t)N_NODES) d = N_NODES - 1;
        atomicAdd(&h[d / NODES_PER_BUCKET], 1);
    }
    __syncthreads();
    if (tid < NB_BUCKET) {
        int c = h[tid];
        partial[blockIdx.x * NB_BUCKET + tid] = c;
        if (c) atomicAdd(&btotal[tid], c);   // non-returning, 65K total
    }
}

__global__ __launch_bounds__(256) void kb_base(const int* __restrict__ btotal,
                                               int* __restrict__ bbase) {
    __shared__ int sh[NB_BUCKET];
    int tid = threadIdx.x;
    sh[tid] = btotal[tid];
    __syncthreads();
    for (int off = 1; off < NB_BUCKET; off <<= 1) {
        int t = (tid >= off) ? sh[tid - off] : 0;
        __syncthreads();
        sh[tid] += t;
        __syncthreads();
    }
    bbase[tid + 1] = sh[tid];
    if (tid == 0) bbase[0] = 0;
}

__global__ __launch_bounds__(256) void kb_scan(const int* __restrict__ partial,
                                               const int* __restrict__ bbase,
                                               int* __restrict__ goff) {
    __shared__ int sh[NBLK];
    int b = blockIdx.x, tid = threadIdx.x;
    sh[tid] = partial[tid * NB_BUCKET + b];
    __syncthreads();
    for (int off = 1; off < NBLK; off <<= 1) {
        int t = (tid >= off) ? sh[tid - off] : 0;
        __syncthreads();
        sh[tid] += t;
        __syncthreads();
    }
    int excl = (tid == 0) ? 0 : sh[tid - 1];
    goff[tid * NB_BUCKET + b] = bbase[b] + excl;
}

__global__ __launch_bounds__(512) void kb_scatter(const int* __restrict__ src,
                                                  const int* __restrict__ dst,
                                                  const int* __restrict__ goff,
                                                  int* __restrict__ ebuf) {
    __shared__ int cur[NB_BUCKET];
    int tid = threadIdx.x;
    if (tid < NB_BUCKET) cur[tid] = goff[blockIdx.x * NB_BUCKET + tid];
    __syncthreads();
    int e0 = blockIdx.x * EDGES_PER_BLK;
    for (int i = tid; i < EDGES_PER_BLK; i += 512) {
        uint_t d = (uint_t)dst[e0 + i];
        if (d >= (uint_t)N_NODES) d = N_NODES - 1;
        uint_t s = (uint_t)src[e0 + i];
        if (s >= (uint_t)N_NODES) s = 0;
        int b = (int)(d / NODES_PER_BUCKET);
        int dl = (int)d - b * NODES_PER_BUCKET;     // < 391, 9 bits
        int pos = atomicAdd(&cur[b], 1);            // LDS returning atomic
        ebuf[pos] = (dl << 17) | (int)s;            // src < 2^17
    }
}

__global__ __launch_bounds__(512) void kb_csr(const int* __restrict__ ebuf,
                                              const int* __restrict__ bbase,
                                              int* __restrict__ row_ptr,
                                              int* __restrict__ col_src) {
    __shared__ int cnt[512];
    __shared__ int sh[512];
    __shared__ int off[512];
    int tid = threadIdx.x, b = blockIdx.x;
    int s0 = bbase[b], s1 = bbase[b + 1];
    int n = s1 - s0;
    cnt[tid] = 0;
    __syncthreads();
    for (int i = tid; i < n; i += 512) {
        int dl = ebuf[s0 + i] >> 17;
        atomicAdd(&cnt[dl], 1);
    }
    __syncthreads();
    sh[tid] = cnt[tid];
    __syncthreads();
    for (int o = 1; o < 512; o <<= 1) {
        int t = (tid >= o) ? sh[tid - o] : 0;
        __syncthreads();
        sh[tid] += t;
        __syncthreads();
    }
    off[tid] = (tid == 0) ? 0 : sh[tid - 1];
    cnt[tid] = 0;

    int node0 = b * NODES_PER_BUCKET;
    int ncnt = N_NODES - node0;
    if (ncnt > NODES_PER_BUCKET) ncnt = NODES_PER_BUCKET;
    if (tid < ncnt) row_ptr[node0 + tid] = s0 + off[tid];
    if (b == NB_BUCKET - 1 && tid == 0) row_ptr[N_NODES] = N_EDGES;
    __syncthreads();

    for (int i = tid; i < n; i += 512) {
        int v = ebuf[s0 + i];
        int dl = v >> 17;
        int r = atomicAdd(&cnt[dl], 1);             // LDS returning atomic
        col_src[s0 + off[dl] + r] = v & 0x1FFFF;
    }
}

// ---------------- aggregation on bf16 y (dim 64) -> bf16 u (R2-proven version) ----------------
__global__ __launch_bounds__(256) void k_aggregate_u(const uint2* __restrict__ y2,
                                                     const int* __restrict__ row_ptr,
                                                     const int* __restrict__ col_src,
                                                     const float* __restrict__ eps, int layer,
                                                     const float* __restrict__ b1,
                                                     uint2* __restrict__ u2) {
    int wid = threadIdx.x >> 6, lane = threadIdx.x & 63;
    int gid = lane >> 4, l4 = lane & 15;
    float one_eps = 1.0f + eps[layer];
    int stride = gridDim.x * 4;

    for (int node = blockIdx.x * 4 + wid; node < N_NODES; node += stride) {
        int e0 = row_ptr[node], e1 = row_ptr[node + 1];
        if (e0 < 0) e0 = 0;
        if (e1 > N_EDGES) e1 = N_EDGES;
        if (e1 < e0) e1 = e0;

        float4 a0 = {0.f, 0.f, 0.f, 0.f}, a1 = a0, a2 = a0, a3 = a0;

        for (int ebase = e0; ebase < e1; ebase += 64) {
            int len = e1 - ebase; if (len > 64) len = 64;
            // one coalesced load of up to 64 edge sources (clamped; e1 >= 1 here)
            int ci = ebase + lane; if (ci > e1 - 1) ci = e1 - 1;
            int sv = col_src[ci];
            sv = (int)min((uint_t)sv, (uint_t)(N_NODES - 1));

            int nfull = len >> 2;   // steps of 4 edges
            int rem = len & 3;
            int j = 0;
            for (; j + 4 <= nfull; j += 4) {
                int s0 = __shfl(sv, (j + 0) * 4 + gid, 64);
                int s1 = __shfl(sv, (j + 1) * 4 + gid, 64);
                int s2 = __shfl(sv, (j + 2) * 4 + gid, 64);
                int s3 = __shfl(sv, (j + 3) * 4 + gid, 64);
                uint2 w0 = y2[(size_t)s0 * 16 + l4];
                uint2 w1 = y2[(size_t)s1 * 16 + l4];
                uint2 w2 = y2[(size_t)s2 * 16 + l4];
                uint2 w3 = y2[(size_t)s3 * 16 + l4];
                a0.x += lo_bf(w0.x); a0.y += hi_bf(w0.x); a0.z += lo_bf(w0.y); a0.w += hi_bf(w0.y);
                a1.x += lo_bf(w1.x); a1.y += hi_bf(w1.x); a1.z += lo_bf(w1.y); a1.w += hi_bf(w1.y);
                a2.x += lo_bf(w2.x); a2.y += hi_bf(w2.x); a2.z += lo_bf(w2.y); a2.w += hi_bf(w2.y);
                a3.x += lo_bf(w3.x); a3.y += hi_bf(w3.x); a3.z += lo_bf(w3.y); a3.w += hi_bf(w3.y);
            }
            for (; j < nfull; ++j) {
                int s = __shfl(sv, j * 4 + gid, 64);
                uint2 w = y2[(size_t)s * 16 + l4];
                a0.x += lo_bf(w.x); a0.y += hi_bf(w.x); a0.z += lo_bf(w.y); a0.w += hi_bf(w.y);
            }
            if (rem) {
                int s = __shfl(sv, nfull * 4 + gid, 64);
                if (gid < rem) {
                    uint2 w = y2[(size_t)s * 16 + l4];
                    a1.x += lo_bf(w.x); a1.y += hi_bf(w.x); a1.z += lo_bf(w.y); a1.w += hi_bf(w.y);
                }
            }
        }

        float4 t;
        t.x = (a0.x + a1.x) + (a2.x + a3.x);
        t.y = (a0.y + a1.y) + (a2.y + a3.y);
        t.z = (a0.z + a1.z) + (a2.z + a3.z);
        t.w = (a0.w + a1.w) + (a2.w + a3.w);
        t.x += __shfl_xor(t.x, 16, 64); t.x += __shfl_xor(t.x, 32, 64);
        t.y += __shfl_xor(t.y, 16, 64); t.y += __shfl_xor(t.y, 32, 64);
        t.z += __shfl_xor(t.z, 16, 64); t.z += __shfl_xor(t.z, 32, 64);
        t.w += __shfl_xor(t.w, 16, 64); t.w += __shfl_xor(t.w, 32, 64);

        if (gid == 0) {
            uint2 ws = y2[(size_t)node * 16 + l4];
            float4 bb = *(const float4*)&b1[4 * l4];
            float ox = t.x + one_eps * lo_bf(ws.x) + bb.x;
            float oy = t.y + one_eps * hi_bf(ws.x) + bb.y;
            float oz = t.z + one_eps * lo_bf(ws.y) + bb.z;
            float ow = t.w + one_eps * hi_bf(ws.y) + bb.w;
            uint2 o2;
            o2.x = pack2(ox, oy);
            o2.y = pack2(oz, ow);
            u2[(size_t)node * 16 + l4] = o2;
        }
    }
}

// ---------------- column stats over bf16 u [N_NODES x 64] (R2-proven) ----------------
__global__ __launch_bounds__(256) void k_stats(const uint2* __restrict__ u2, float* __restrict__ sums) {
    __shared__ float sh[256 * 8];
    int tid = threadIdx.x;
    float a[4] = {0.f, 0.f, 0.f, 0.f}, b[4] = {0.f, 0.f, 0.f, 0.f};
    for (size_t i = (size_t)blockIdx.x * 256 + tid; i < (size_t)N_NODES * 16; i += (size_t)gridDim.x * 256) {
        uint2 w = u2[i];
        float v0 = lo_bf(w.x), v1 = hi_bf(w.x), v2 = lo_bf(w.y), v3 = hi_bf(w.y);
        a[0] += v0; b[0] += v0 * v0;
        a[1] += v1; b[1] += v1 * v1;
        a[2] += v2; b[2] += v2 * v2;
        a[3] += v3; b[3] += v3 * v3;
    }
    #pragma unroll
    for (int j = 0; j < 4; ++j) { sh[tid * 8 + j] = a[j]; sh[tid * 8 + 4 + j] = b[j]; }
    __syncthreads();
    if (tid < 64) {
        int quad = tid >> 2, o = tid & 3;
        float s = 0.f, ss = 0.f;
        for (int g = 0; g < 16; ++g) {
            int t = g * 16 + quad;
            s  += sh[t * 8 + o];
            ss += sh[t * 8 + 4 + o];
        }
        atomicAdd(&sums[tid], s);
        atomicAdd(&sums[64 + tid], ss);
    }
}

// ---------------- GEMM1 (layer 0 only): ybf = bf16(x @ W1_0) ----------------
template <int K>
__global__ __launch_bounds__(256) void k_gemm1(const float* __restrict__ A,
                                               const float* __restrict__ W,
                                               ushort_t* __restrict__ out) {
    constexpr int KP = K + 4;
    constexpr int KQ = K / 4;
    __shared__ float Al[64 * KP];
    __shared__ float Wl[K * 64];
    int tid = threadIdx.x;
    int base = blockIdx.x * 64;

    for (int i = tid; i < K * 16; i += 256)
        ((float4*)Wl)[i] = ((const float4*)W)[i];

    if (base + 64 <= N_NODES) {
        const float4* Ag = (const float4*)(A + (size_t)base * K);
        for (int i = tid; i < 16 * K; i += 256) {
            int row = i / KQ, kk = (i % KQ) * 4;
            float4 v = Ag[i];
            *(float4*)&Al[row * KP + kk] = v;
        }
    } else {
        for (int i = tid; i < 16 * K; i += 256) {
            int row = i / KQ, kk = (i % KQ) * 4;
            int grow = base + row; if (grow >= N_NODES) grow = N_NODES - 1;
            float4 v = ((const float4*)(A + (size_t)grow * K))[i % KQ];
            *(float4*)&Al[row * KP + kk] = v;
        }
    }
    __syncthreads();

    int ct = (tid & 15) * 4;
    int rb = (tid >> 4) * 4;
    float4 acc0 = {0.f, 0.f, 0.f, 0.f}, acc1 = acc0, acc2 = acc0, acc3 = acc0;
    const float* A0 = &Al[(rb + 0) * KP];
    const float* A1 = &Al[(rb + 1) * KP];
    const float* A2 = &Al[(rb + 2) * KP];
    const float* A3 = &Al[(rb + 3) * KP];
    #pragma unroll 4
    for (int k = 0; k < K; ++k) {
        float4 w = *(const float4*)&Wl[k * 64 + ct];
        float a0 = A0[k], a1 = A1[k], a2 = A2[k], a3 = A3[k];
        acc0.x = fmaf(a0, w.x, acc0.x); acc0.y = fmaf(a0, w.y, acc0.y);
        acc0.z = fmaf(a0, w.z, acc0.z); acc0.w = fmaf(a0, w.w, acc0.w);
        acc1.x = fmaf(a1, w.x, acc1.x); acc1.y = fmaf(a1, w.y, acc1.y);
        acc1.z = fmaf(a1, w.z, acc1.z); acc1.w = fmaf(a1, w.w, acc1.w);
        acc2.x = fmaf(a2, w.x, acc2.x); acc2.y = fmaf(a2, w.y, acc2.y);
        acc2.z = fmaf(a2, w.z, acc2.z); acc2.w = fmaf(a2, w.w, acc2.w);
        acc3.x = fmaf(a3, w.x, acc3.x); acc3.y = fmaf(a3, w.y, acc3.y);
        acc3.z = fmaf(a3, w.z, acc3.z); acc3.w = fmaf(a3, w.w, acc3.w);
    }

    float4 accs[4] = {acc0, acc1, acc2, acc3};
    #pragma unroll
    for (int r = 0; r < 4; ++r) {
        int row = base + rb + r;
        if (row < N_NODES) {
            ushort4 o;
            o.x = f2bf(accs[r].x); o.y = f2bf(accs[r].y);
            o.z = f2bf(accs[r].z); o.w = f2bf(accs[r].w);
            *(ushort4*)&out[(size_t)row * 64 + ct] = o;
        }
    }
}

// ---------------- fused layer tail (bf16 u input), persistent, shared weight buffer ----------------
template <bool NEXT>
__global__ __launch_bounds__(256) void k_fused(const uint2* __restrict__ U2,
                                               const float* __restrict__ W2,
                                               const float* __restrict__ sums,
                                               const float* __restrict__ g_,
                                               const float* __restrict__ be,
                                               const float* __restrict__ b2,
                                               const int* __restrict__ batch,
                                               float* __restrict__ pooled, int layer,
                                               const float* __restrict__ W1n,
                                               ushort_t* __restrict__ ynext) {
    constexpr int K = 64, KP = 68, KQ = 16;
    __shared__ float Al[64 * KP];       // 17408 B
    __shared__ float Wl[K * 64];        // 16384 B (time-shared: W2 then W1n)
    __shared__ float Pl[256];
    __shared__ __align__(16) float Sc[64];
    __shared__ __align__(16) float Sh[64];
    int tid = threadIdx.x;

    if (tid < 64) {
        const float inv_n = 1.0f / N_NODES;
        float mean = sums[tid] * inv_n;
        float var = sums[64 + tid] * inv_n - mean * mean;
        if (var < 0.f) var = 0.f;
        float inv = rsqrtf(var + 1e-5f);
        float sc = inv * g_[tid];
        Sc[tid] = sc;
        Sh[tid] = be[tid] - mean * sc;
    }
    __syncthreads();

    int ct = (tid & 15) * 4;
    int rb = (tid >> 4) * 4;

    for (int tile = blockIdx.x; tile < N_TILES; tile += gridDim.x) {
        int base = tile * 64;

        // load Wl <- W2 ; build Al = relu(BN(u))
        for (int i = tid; i < K * 16; i += 256)
            ((float4*)Wl)[i] = ((const float4*)W2)[i];
        {
            bool full = (base + 64 <= N_NODES);
            for (int i = tid; i < 16 * K; i += 256) {
                int row = i / KQ, kq = i % KQ, kk = kq * 4;
                int grow = base + row;
                if (!full && grow >= N_NODES) grow = N_NODES - 1;
                uint2 w = U2[(size_t)grow * 16 + kq];
                float4 v = {lo_bf(w.x), hi_bf(w.x), lo_bf(w.y), hi_bf(w.y)};
                float4 sc = *(const float4*)&Sc[kk];
                float4 sh = *(const float4*)&Sh[kk];
                v.x = fmaxf(fmaf(v.x, sc.x, sh.x), 0.f);
                v.y = fmaxf(fmaf(v.y, sc.y, sh.y), 0.f);
                v.z = fmaxf(fmaf(v.z, sc.z, sh.z), 0.f);
                v.w = fmaxf(fmaf(v.w, sc.w, sh.w), 0.f);
                *(float4*)&Al[row * KP + kk] = v;
            }
        }
        __syncthreads();

        // GEMM1: h = Al(u) @ Wl(W2)
        float4 acc0 = {0.f, 0.f, 0.f, 0.f}, acc1 = acc0, acc2 = acc0, acc3 = acc0;
        {
            const float* A0 = &Al[(rb + 0) * KP];
            const float* A1 = &Al[(rb + 1) * KP];
            const float* A2 = &Al[(rb + 2) * KP];
            const float* A3 = &Al[(rb + 3) * KP];
            #pragma unroll 4
            for (int k = 0; k < K; ++k) {
                float4 w = *(const float4*)&Wl[k * 64 + ct];
                float a0 = A0[k], a1 = A1[k], a2 = A2[k], a3 = A3[k];
                acc0.x = fmaf(a0, w.x, acc0.x); acc0.y = fmaf(a0, w.y, acc0.y);
                acc0.z = fmaf(a0, w.z, acc0.z); acc0.w = fmaf(a0, w.w, acc0.w);
                acc1.x = fmaf(a1, w.x, acc1.x); acc1.y = fmaf(a1, w.y, acc1.y);
                acc1.z = fmaf(a1, w.z, acc1.z); acc1.w = fmaf(a1, w.w, acc1.w);
                acc2.x = fmaf(a2, w.x, acc2.x); acc2.y = fmaf(a2, w.y, acc2.y);
                acc2.z = fmaf(a2, w.z, acc2.z); acc2.w = fmaf(a2, w.w, acc2.w);
                acc3.x = fmaf(a3, w.x, acc3.x); acc3.y = fmaf(a3, w.y, acc3.y);
                acc3.z = fmaf(a3, w.z, acc3.z); acc3.w = fmaf(a3, w.w, acc3.w);
            }
        }
        __syncthreads();   // done reading Al(u) and Wl(W2)

        // write h into Al; load Wl <- W1n (different buffers, both writes)
        {
            float4 bb = *(const float4*)&b2[ct];
            float4 accs[4] = {acc0, acc1, acc2, acc3};
            #pragma unroll
            for (int r = 0; r < 4; ++r) {
                float4 o;
                o.x = fmaxf(accs[r].x + bb.x, 0.f);
                o.y = fmaxf(accs[r].y + bb.y, 0.f);
                o.z = fmaxf(accs[r].z + bb.z, 0.f);
                o.w = fmaxf(accs[r].w + bb.w, 0.f);
                *(float4*)&Al[(rb + r) * KP + ct] = o;
            }
        }
        if (NEXT) {
            for (int i = tid; i < K * 16; i += 256)
                ((float4*)Wl)[i] = ((const float4*)W1n)[i];
        }
        __syncthreads();   // h tile + W1n ready

        // GEMM2 first (no internal barriers): ynext = bf16(h @ W1n)
        if (NEXT) {
            float4 y0 = {0.f, 0.f, 0.f, 0.f}, y1 = y0, y2_ = y0, y3 = y0;
            const float* A0 = &Al[(rb + 0) * KP];
            const float* A1 = &Al[(rb + 1) * KP];
            const float* A2 = &Al[(rb + 2) * KP];
            const float* A3 = &Al[(rb + 3) * KP];
            #pragma unroll 4
            for (int k = 0; k < K; ++k) {
                float4 w = *(const float4*)&Wl[k * 64 + ct];
                float a0 = A0[k], a1 = A1[k], a2 = A2[k], a3 = A3[k];
                y0.x = fmaf(a0, w.x, y0.x); y0.y = fmaf(a0, w.y, y0.y);
                y0.z = fmaf(a0, w.z, y0.z); y0.w = fmaf(a0, w.w, y0.w);
                y1.x = fmaf(a1, w.x, y1.x); y1.y = fmaf(a1, w.y, y1.y);
                y1.z = fmaf(a1, w.z, y1.z); y1.w = fmaf(a1, w.w, y1.w);
                y2_.x = fmaf(a2, w.x, y2_.x); y2_.y = fmaf(a2, w.y, y2_.y);
                y2_.z = fmaf(a2, w.z, y2_.z); y2_.w = fmaf(a2, w.w, y2_.w);
                y3.x = fmaf(a3, w.x, y3.x); y3.y = fmaf(a3, w.y, y3.y);
                y3.z = fmaf(a3, w.z, y3.z); y3.w = fmaf(a3, w.w, y3.w);
            }
            float4 ys[4] = {y0, y1, y2_, y3};
            #pragma unroll
            for (int r = 0; r < 4; ++r) {
                int row = base + rb + r;
                if (row < N_NODES) {
                    ushort4 o;
                    o.x = f2bf(ys[r].x); o.y = f2bf(ys[r].y);
                    o.z = f2bf(ys[r].z); o.w = f2bf(ys[r].w);
                    *(ushort4*)&ynext[(size_t)row * 64 + ct] = o;
                }
            }
        }

        // pooling over graph segments (batch sorted); internal barriers
        {
            int lastEx = base + 64; if (lastEx > N_NODES) lastEx = N_NODES;
            int gstart = batch[base];
            int gend = batch[lastEx - 1];
            if (gstart < 0) gstart = 0;
            if (gend > N_GRAPHS - 1) gend = N_GRAPHS - 1;
            int col = tid & 63, q = tid >> 6;
            int rs = base;
            for (int g = gstart; g <= gend; ++g) {
                int lo = rs, hi = lastEx;
                while (lo < hi) { int mid = (lo + hi) >> 1; if (batch[mid] <= g) lo = mid + 1; else hi = mid; }
                int re = lo;
                float s = 0.f;
                for (int r = rs + q; r < re; r += 4) s += Al[(r - base) * KP + col];
                Pl[tid] = s;
                __syncthreads();
                if (tid < 64) {
                    float tot = (Pl[col] + Pl[64 + col]) + (Pl[128 + col] + Pl[192 + col]);
                    atomicAdd(&pooled[g * 256 + layer * 64 + col], tot);
                }
                __syncthreads();
                rs = re;
            }
        }
        __syncthreads();   // tile end: Al/Wl safe to overwrite
    }
}

// ---------------- head ----------------
__global__ __launch_bounds__(64) void k_head1(const float* __restrict__ pooled,
                                              const float* __restrict__ W, const float* __restrict__ b,
                                              float* __restrict__ t1) {
    __shared__ __align__(16) float pl[256];
    int g = blockIdx.x, lane = threadIdx.x;
    ((float4*)pl)[lane] = ((const float4*)(pooled + g * 256))[lane];
    __syncthreads();
    float acc = b[lane];
    for (int k = 0; k < 256; ++k) acc += pl[k] * W[k * 64 + lane];
    t1[g * 64 + lane] = acc;
}

__global__ __launch_bounds__(64) void k_head3(const float* __restrict__ t1,
                                              const float* __restrict__ g_, const float* __restrict__ b_,
                                              const float* __restrict__ W2, const float* __restrict__ b2,
                                              float* __restrict__ out) {
    __shared__ float v[64];
    __shared__ float o[16];
    int g = blockIdx.x, lane = threadIdx.x;
    float s = 0.f, q = 0.f;
    for (int r = 0; r < N_GRAPHS; ++r) {
        float vv = t1[r * 64 + lane];
        s += vv; q += vv * vv;
    }
    float mean = s * (1.0f / N_GRAPHS);
    float var = q * (1.0f / N_GRAPHS) - mean * mean;
    if (var < 0.f) var = 0.f;
    float inv = rsqrtf(var + 1e-5f);
    float sc = inv * g_[lane];
    float sh = b_[lane] - mean * sc;
    float x = t1[g * 64 + lane] * sc + sh;
    v[lane] = fmaxf(x, 0.f);
    __syncthreads();
    if (lane < N_CLASSES) {
        float acc = b2[lane];
        for (int k = 0; k < 64; ++k) acc += v[k] * W2[k * N_CLASSES + lane];
        o[lane] = acc;
    }
    __syncthreads();
    if (lane < N_CLASSES) {
        float m = -1e30f;
        for (int k = 0; k < N_CLASSES; ++k) m = fmaxf(m, o[k]);
        float ssum = 0.f;
        for (int k = 0; k < N_CLASSES; ++k) ssum += expf(o[k] - m);
        out[g * N_CLASSES + lane] = o[lane] - m - logf(ssum);
    }
}

// ---------------- launch ----------------
extern "C" void kernel_launch(void* const* d_in, const int* in_sizes, int n_in,
                              void* d_out, int out_size, void* d_ws, size_t ws_size,
                              hipStream_t stream) {
    const float* x      = (const float*)d_in[0];
    const int*   ei     = (const int*)d_in[1];
    const int*   srcArr = ei;
    const int*   dstArr = ei + N_EDGES;
    const int*   batch  = (const int*)d_in[2];
    const float* eps    = (const float*)d_in[3];
    const float* W1_0   = (const float*)d_in[4];
    const float* b1_0   = (const float*)d_in[5];
    const float* g_0    = (const float*)d_in[6];
    const float* be_0   = (const float*)d_in[7];
    const float* W2_0   = (const float*)d_in[8];
    const float* b2_0   = (const float*)d_in[9];
    const float* W1_r   = (const float*)d_in[10];
    const float* b1_r   = (const float*)d_in[11];
    const float* g_r    = (const float*)d_in[12];
    const float* be_r   = (const float*)d_in[13];
    const float* W2_r   = (const float*)d_in[14];
    const float* b2_r   = (const float*)d_in[15];
    const float* lin1W  = (const float*)d_in[16];
    const float* lin1b  = (const float*)d_in[17];
    const float* bn_g   = (const float*)d_in[18];
    const float* bn_b   = (const float*)d_in[19];
    const float* lin2W  = (const float*)d_in[20];
    const float* lin2b  = (const float*)d_in[21];

    char* ws = (char*)d_ws;
    auto alloc = [&](size_t bytes) {
        char* p = ws;
        ws += (bytes + 255) & ~(size_t)255;
        return p;
    };
    int*      row_ptr = (int*)alloc(((size_t)N_NODES + 1) * 4);
    int*      col_src = (int*)alloc((size_t)N_EDGES * 4);
    int*      ebuf    = (int*)alloc((size_t)N_EDGES * 4);
    int*      partial = (int*)alloc((size_t)NBLK * NB_BUCKET * 4);
    int*      goff    = (int*)alloc((size_t)NBLK * NB_BUCKET * 4);
    int*      btotal  = (int*)alloc((size_t)NB_BUCKET * 4);
    int*      bbase   = (int*)alloc(((size_t)NB_BUCKET + 1) * 4);
    ushort_t* ybf     = (ushort_t*)alloc((size_t)N_NODES * 64 * 2);
    ushort_t* ubf     = (ushort_t*)alloc((size_t)N_NODES * 64 * 2);
    float*    statsA  = (float*)alloc(NLAYERS * 128 * 4);
    float*    pooled  = (float*)alloc((size_t)N_GRAPHS * 256 * 4);
    float*    t1      = (float*)alloc((size_t)N_GRAPHS * 64 * 4);

    k_zero<<<(N_GRAPHS * 256 + 255) / 256, 256, 0, stream>>>(btotal, statsA, pooled);
    kb_hist<<<NBLK, 512, 0, stream>>>(dstArr, partial, btotal);
    kb_base<<<1, 256, 0, stream>>>(btotal, bbase);
    kb_scan<<<NB_BUCKET, 256, 0, stream>>>(partial, bbase, goff);
    kb_scatter<<<NBLK, 512, 0, stream>>>(srcArr, dstArr, goff, ebuf);
    kb_csr<<<NB_BUCKET, 512, 0, stream>>>(ebuf, bbase, row_ptr, col_src);

    const int gemm_grid = (N_NODES + 63) / 64;      // 1563

    // layer 0 front GEMM: y0 = bf16(x @ W1_0)
    k_gemm1<128><<<gemm_grid, 256, 0, stream>>>(x, W1_0, ybf);

    for (int l = 0; l < NLAYERS; ++l) {
        const float *b1, *gg, *be, *W2, *b2;
        if (l == 0) { b1 = b1_0; gg = g_0; be = be_0; W2 = W2_0; b2 = b2_0; }
        else {
            b1 = b1_r + (size_t)(l - 1) * 64;
            gg = g_r  + (size_t)(l - 1) * 64;
            be = be_r + (size_t)(l - 1) * 64;
            W2 = W2_r + (size_t)(l - 1) * 64 * 64;
            b2 = b2_r + (size_t)(l - 1) * 64;
        }
        k_aggregate_u<<<NAGG, 256, 0, stream>>>((const uint2*)ybf, row_ptr, col_src, eps, l, b1,
                                                (uint2*)ubf);
        k_stats<<<512, 256, 0, stream>>>((const uint2*)ubf, statsA + l * 128);
        if (l < NLAYERS - 1) {
            const float* W1n = W1_r + (size_t)l * 64 * 64;
            k_fused<true><<<FUSED_GRID, 256, 0, stream>>>((const uint2*)ubf, W2, statsA + l * 128, gg, be, b2,
                                                          batch, pooled, l, W1n, ybf);
        } else {
            k_fused<false><<<FUSED_GRID, 256, 0, stream>>>((const uint2*)ubf, W2, statsA + l * 128, gg, be, b2,
                                                           batch, pooled, l, nullptr, nullptr);
        }
    }

    k_head1<<<N_GRAPHS, 64, 0, stream>>>(pooled, lin1W, lin1b, t1);
    k_head3<<<N_GRAPHS, 64, 0, stream>>>(t1, bn_g, bn_b, lin2W, lin2b, (float*)d_out);
}

// Round 6
// 523.403 us; speedup vs baseline: 1.1539x; 1.0524x over previous
//
#include <hip/hip_runtime.h>

#define N_NODES 100000
#define N_EDGES 1600000
#define F_IN 128
#define HID 64
#define NLAYERS 4
#define N_GRAPHS 512
#define N_CLASSES 10

// bucketed CSR build
#define NB_BUCKET 256
#define NODES_PER_BUCKET 391            // ceil(100000/256); 256*391 = 100096
#define NBLK 256
#define EDGES_PER_BLK (N_EDGES / NBLK)  // 6250 exactly

#define N_TILES ((N_NODES + 63) / 64)   // 1563
#define FUSED_GRID 1024                 // 4 blocks/CU x 256 CU (LDS-limited)
#define NAGG 2048                       // aggregate persistent grid
#define NSTAT 512                       // stats grid

typedef unsigned int uint_t;
typedef unsigned short ushort_t;

__device__ __forceinline__ float lo_bf(uint_t w) { return __uint_as_float(w << 16); }
__device__ __forceinline__ float hi_bf(uint_t w) { return __uint_as_float(w & 0xffff0000u); }
__device__ __forceinline__ ushort_t f2bf(float f) {
    uint_t u = __float_as_uint(f);
    u += 0x7fffu + ((u >> 16) & 1u);   // round-to-nearest-even
    return (ushort_t)(u >> 16);
}
__device__ __forceinline__ uint_t pack2(float a, float b) {
    return ((uint_t)f2bf(b) << 16) | (uint_t)f2bf(a);
}

// ---------------- workspace zeroing ----------------
__global__ __launch_bounds__(256) void k_zero(int* __restrict__ btotal,
                                              float* __restrict__ statsA,
                                              float* __restrict__ pooled) {
    int i = blockIdx.x * 256 + threadIdx.x;
    if (i < NB_BUCKET) btotal[i] = 0;
    if (i < NLAYERS * 128) statsA[i] = 0.f;
    if (i < N_GRAPHS * 256) pooled[i] = 0.f;
}

// ---------------- bucketed CSR build (no global returning atomics) ----------------
__global__ __launch_bounds__(512) void kb_hist(const int* __restrict__ dst,
                                               int* __restrict__ partial,
                                               int* __restrict__ btotal) {
    __shared__ int h[NB_BUCKET];
    int tid = threadIdx.x;
    if (tid < NB_BUCKET) h[tid] = 0;
    __syncthreads();
    int e0 = blockIdx.x * EDGES_PER_BLK;
    for (int i = tid; i < EDGES_PER_BLK; i += 512) {
        uint_t d = (uint_t)dst[e0 + i];
        if (d >= (uint_t)N_NODES) d = N_NODES - 1;
        atomicAdd(&h[d / NODES_PER_BUCKET], 1);
    }
    __syncthreads();
    if (tid < NB_BUCKET) {
        int c = h[tid];
        partial[blockIdx.x * NB_BUCKET + tid] = c;
        if (c) atomicAdd(&btotal[tid], c);   // non-returning, 65K total
    }
}

__global__ __launch_bounds__(256) void kb_base(const int* __restrict__ btotal,
                                               int* __restrict__ bbase) {
    __shared__ int sh[NB_BUCKET];
    int tid = threadIdx.x;
    sh[tid] = btotal[tid];
    __syncthreads();
    for (int off = 1; off < NB_BUCKET; off <<= 1) {
        int t = (tid >= off) ? sh[tid - off] : 0;
        __syncthreads();
        sh[tid] += t;
        __syncthreads();
    }
    bbase[tid + 1] = sh[tid];
    if (tid == 0) bbase[0] = 0;
}

__global__ __launch_bounds__(256) void kb_scan(const int* __restrict__ partial,
                                               const int* __restrict__ bbase,
                                               int* __restrict__ goff) {
    __shared__ int sh[NBLK];
    int b = blockIdx.x, tid = threadIdx.x;
    sh[tid] = partial[tid * NB_BUCKET + b];
    __syncthreads();
    for (int off = 1; off < NBLK; off <<= 1) {
        int t = (tid >= off) ? sh[tid - off] : 0;
        __syncthreads();
        sh[tid] += t;
        __syncthreads();
    }
    int excl = (tid == 0) ? 0 : sh[tid - 1];
    goff[tid * NB_BUCKET + b] = bbase[b] + excl;
}

__global__ __launch_bounds__(512) void kb_scatter(const int* __restrict__ src,
                                                  const int* __restrict__ dst,
                                                  const int* __restrict__ goff,
                                                  int* __restrict__ ebuf) {
    __shared__ int cur[NB_BUCKET];
    int tid = threadIdx.x;
    if (tid < NB_BUCKET) cur[tid] = goff[blockIdx.x * NB_BUCKET + tid];
    __syncthreads();
    int e0 = blockIdx.x * EDGES_PER_BLK;
    for (int i = tid; i < EDGES_PER_BLK; i += 512) {
        uint_t d = (uint_t)dst[e0 + i];
        if (d >= (uint_t)N_NODES) d = N_NODES - 1;
        uint_t s = (uint_t)src[e0 + i];
        if (s >= (uint_t)N_NODES) s = 0;
        int b = (int)(d / NODES_PER_BUCKET);
        int dl = (int)d - b * NODES_PER_BUCKET;     // < 391, 9 bits
        int pos = atomicAdd(&cur[b], 1);            // LDS returning atomic
        ebuf[pos] = (dl << 17) | (int)s;            // src < 2^17
    }
}

__global__ __launch_bounds__(512) void kb_csr(const int* __restrict__ ebuf,
                                              const int* __restrict__ bbase,
                                              int* __restrict__ row_ptr,
                                              int* __restrict__ col_src) {
    __shared__ int cnt[512];
    __shared__ int sh[512];
    __shared__ int off[512];
    int tid = threadIdx.x, b = blockIdx.x;
    int s0 = bbase[b], s1 = bbase[b + 1];
    int n = s1 - s0;
    cnt[tid] = 0;
    __syncthreads();
    for (int i = tid; i < n; i += 512) {
        int dl = ebuf[s0 + i] >> 17;
        atomicAdd(&cnt[dl], 1);
    }
    __syncthreads();
    sh[tid] = cnt[tid];
    __syncthreads();
    for (int o = 1; o < 512; o <<= 1) {
        int t = (tid >= o) ? sh[tid - o] : 0;
        __syncthreads();
        sh[tid] += t;
        __syncthreads();
    }
    off[tid] = (tid == 0) ? 0 : sh[tid - 1];
    cnt[tid] = 0;

    int node0 = b * NODES_PER_BUCKET;
    int ncnt = N_NODES - node0;
    if (ncnt > NODES_PER_BUCKET) ncnt = NODES_PER_BUCKET;
    if (tid < ncnt) row_ptr[node0 + tid] = s0 + off[tid];
    if (b == NB_BUCKET - 1 && tid == 0) row_ptr[N_NODES] = N_EDGES;
    __syncthreads();

    for (int i = tid; i < n; i += 512) {
        int v = ebuf[s0 + i];
        int dl = v >> 17;
        int r = atomicAdd(&cnt[dl], 1);             // LDS returning atomic
        col_src[s0 + off[dl] + r] = v & 0x1FFFF;
    }
}

// ---------------- aggregation on bf16 y (dim 64) -> bf16 u (R2-proven version) ----------------
__global__ __launch_bounds__(256) void k_aggregate_u(const uint2* __restrict__ y2,
                                                     const int* __restrict__ row_ptr,
                                                     const int* __restrict__ col_src,
                                                     const float* __restrict__ eps, int layer,
                                                     const float* __restrict__ b1,
                                                     uint2* __restrict__ u2) {
    int wid = threadIdx.x >> 6, lane = threadIdx.x & 63;
    int gid = lane >> 4, l4 = lane & 15;
    float one_eps = 1.0f + eps[layer];
    int stride = gridDim.x * 4;

    for (int node = blockIdx.x * 4 + wid; node < N_NODES; node += stride) {
        int e0 = row_ptr[node], e1 = row_ptr[node + 1];
        if (e0 < 0) e0 = 0;
        if (e1 > N_EDGES) e1 = N_EDGES;
        if (e1 < e0) e1 = e0;

        float4 a0 = {0.f, 0.f, 0.f, 0.f}, a1 = a0, a2 = a0, a3 = a0;

        for (int ebase = e0; ebase < e1; ebase += 64) {
            int len = e1 - ebase; if (len > 64) len = 64;
            // one coalesced load of up to 64 edge sources (clamped; e1 >= 1 here)
            int ci = ebase + lane; if (ci > e1 - 1) ci = e1 - 1;
            int sv = col_src[ci];
            sv = (int)min((uint_t)sv, (uint_t)(N_NODES - 1));

            int nfull = len >> 2;   // steps of 4 edges
            int rem = len & 3;
            int j = 0;
            for (; j + 4 <= nfull; j += 4) {
                int s0 = __shfl(sv, (j + 0) * 4 + gid, 64);
                int s1 = __shfl(sv, (j + 1) * 4 + gid, 64);
                int s2 = __shfl(sv, (j + 2) * 4 + gid, 64);
                int s3 = __shfl(sv, (j + 3) * 4 + gid, 64);
                uint2 w0 = y2[(size_t)s0 * 16 + l4];
                uint2 w1 = y2[(size_t)s1 * 16 + l4];
                uint2 w2 = y2[(size_t)s2 * 16 + l4];
                uint2 w3 = y2[(size_t)s3 * 16 + l4];
                a0.x += lo_bf(w0.x); a0.y += hi_bf(w0.x); a0.z += lo_bf(w0.y); a0.w += hi_bf(w0.y);
                a1.x += lo_bf(w1.x); a1.y += hi_bf(w1.x); a1.z += lo_bf(w1.y); a1.w += hi_bf(w1.y);
                a2.x += lo_bf(w2.x); a2.y += hi_bf(w2.x); a2.z += lo_bf(w2.y); a2.w += hi_bf(w2.y);
                a3.x += lo_bf(w3.x); a3.y += hi_bf(w3.x); a3.z += lo_bf(w3.y); a3.w += hi_bf(w3.y);
            }
            for (; j < nfull; ++j) {
                int s = __shfl(sv, j * 4 + gid, 64);
                uint2 w = y2[(size_t)s * 16 + l4];
                a0.x += lo_bf(w.x); a0.y += hi_bf(w.x); a0.z += lo_bf(w.y); a0.w += hi_bf(w.y);
            }
            if (rem) {
                int s = __shfl(sv, nfull * 4 + gid, 64);
                if (gid < rem) {
                    uint2 w = y2[(size_t)s * 16 + l4];
                    a1.x += lo_bf(w.x); a1.y += hi_bf(w.x); a1.z += lo_bf(w.y); a1.w += hi_bf(w.y);
                }
            }
        }

        float4 t;
        t.x = (a0.x + a1.x) + (a2.x + a3.x);
        t.y = (a0.y + a1.y) + (a2.y + a3.y);
        t.z = (a0.z + a1.z) + (a2.z + a3.z);
        t.w = (a0.w + a1.w) + (a2.w + a3.w);
        t.x += __shfl_xor(t.x, 16, 64); t.x += __shfl_xor(t.x, 32, 64);
        t.y += __shfl_xor(t.y, 16, 64); t.y += __shfl_xor(t.y, 32, 64);
        t.z += __shfl_xor(t.z, 16, 64); t.z += __shfl_xor(t.z, 32, 64);
        t.w += __shfl_xor(t.w, 16, 64); t.w += __shfl_xor(t.w, 32, 64);

        if (gid == 0) {
            uint2 ws = y2[(size_t)node * 16 + l4];
            float4 bb = *(const float4*)&b1[4 * l4];
            float ox = t.x + one_eps * lo_bf(ws.x) + bb.x;
            float oy = t.y + one_eps * hi_bf(ws.x) + bb.y;
            float oz = t.z + one_eps * lo_bf(ws.y) + bb.z;
            float ow = t.w + one_eps * hi_bf(ws.y) + bb.w;
            uint2 o2;
            o2.x = pack2(ox, oy);
            o2.y = pack2(oz, ow);
            u2[(size_t)node * 16 + l4] = o2;
        }
    }
}

// ---------------- column stats over bf16 u [N_NODES x 64], atomic-free two-stage ----------------
// stage 1: per-block partials[blk][128] (coalesced 512B store per block)
__global__ __launch_bounds__(256) void k_stats(const uint2* __restrict__ u2,
                                               float* __restrict__ partials) {
    __shared__ float sh[256 * 8];
    int tid = threadIdx.x;
    float a[4] = {0.f, 0.f, 0.f, 0.f}, b[4] = {0.f, 0.f, 0.f, 0.f};
    for (size_t i = (size_t)blockIdx.x * 256 + tid; i < (size_t)N_NODES * 16; i += (size_t)gridDim.x * 256) {
        uint2 w = u2[i];
        float v0 = lo_bf(w.x), v1 = hi_bf(w.x), v2 = lo_bf(w.y), v3 = hi_bf(w.y);
        a[0] += v0; b[0] += v0 * v0;
        a[1] += v1; b[1] += v1 * v1;
        a[2] += v2; b[2] += v2 * v2;
        a[3] += v3; b[3] += v3 * v3;
    }
    // thread tid covers column quad q = tid & 15 (grid stride multiple of 16)
    #pragma unroll
    for (int j = 0; j < 4; ++j) { sh[tid * 8 + j] = a[j]; sh[tid * 8 + 4 + j] = b[j]; }
    __syncthreads();
    if (tid < 64) {
        int quad = tid >> 2, o = tid & 3;
        float s = 0.f, ss = 0.f;
        for (int g = 0; g < 16; ++g) {
            int t = g * 16 + quad;
            s  += sh[t * 8 + o];
            ss += sh[t * 8 + 4 + o];
        }
        partials[(size_t)blockIdx.x * 128 + tid]      = s;
        partials[(size_t)blockIdx.x * 128 + 64 + tid] = ss;
    }
}

// stage 2: reduce partials[NSTAT][128] -> statsA layer slice [128]
__global__ __launch_bounds__(256) void k_redstats(const float* __restrict__ partials,
                                                  float* __restrict__ outp) {
    __shared__ float sh[256];
    int b = blockIdx.x, tid = threadIdx.x;
    float v = 0.f;
    for (int i = tid; i < NSTAT; i += 256) v += partials[(size_t)i * 128 + b];
    sh[tid] = v;
    __syncthreads();
    for (int off = 128; off > 0; off >>= 1) {
        if (tid < off) sh[tid] += sh[tid + off];
        __syncthreads();
    }
    if (tid == 0) outp[b] = sh[0];
}

// ---------------- GEMM1 (layer 0 only): ybf = bf16(x @ W1_0), K-chunked for occupancy ----------------
template <int K>
__global__ __launch_bounds__(256) void k_gemm1(const float* __restrict__ A,
                                               const float* __restrict__ W,
                                               ushort_t* __restrict__ out) {
    constexpr int KC = 64;            // K-chunk
    constexpr int KP = KC + 4;        // padded
    __shared__ float Al[64 * KP];     // 17408 B
    __shared__ float Wl[KC * 64];     // 16384 B  -> ~34 KB total, 4 blocks/CU
    int tid = threadIdx.x;
    int base = blockIdx.x * 64;
    int ct = (tid & 15) * 4;
    int rb = (tid >> 4) * 4;
    float4 acc0 = {0.f, 0.f, 0.f, 0.f}, acc1 = acc0, acc2 = acc0, acc3 = acc0;
    bool full = (base + 64 <= N_NODES);

    #pragma unroll
    for (int kc = 0; kc < K; kc += KC) {
        // W chunk: rows kc..kc+KC-1, 64 cols (row-major contiguous)
        for (int i = tid; i < KC * 16; i += 256)
            ((float4*)Wl)[i] = ((const float4*)(W + (size_t)kc * 64))[i];
        // A chunk: 64 rows x KC cols
        for (int i = tid; i < 64 * (KC / 4); i += 256) {
            int row = i / (KC / 4), kq = i % (KC / 4);
            int grow = base + row;
            if (!full && grow >= N_NODES) grow = N_NODES - 1;
            float4 v = ((const float4*)(A + (size_t)grow * K + kc))[kq];
            *(float4*)&Al[row * KP + kq * 4] = v;
        }
        __syncthreads();

        const float* A0 = &Al[(rb + 0) * KP];
        const float* A1 = &Al[(rb + 1) * KP];
        const float* A2 = &Al[(rb + 2) * KP];
        const float* A3 = &Al[(rb + 3) * KP];
        #pragma unroll 4
        for (int k = 0; k < KC; ++k) {
            float4 w = *(const float4*)&Wl[k * 64 + ct];
            float a0 = A0[k], a1 = A1[k], a2 = A2[k], a3 = A3[k];
            acc0.x = fmaf(a0, w.x, acc0.x); acc0.y = fmaf(a0, w.y, acc0.y);
            acc0.z = fmaf(a0, w.z, acc0.z); acc0.w = fmaf(a0, w.w, acc0.w);
            acc1.x = fmaf(a1, w.x, acc1.x); acc1.y = fmaf(a1, w.y, acc1.y);
            acc1.z = fmaf(a1, w.z, acc1.z); acc1.w = fmaf(a1, w.w, acc1.w);
            acc2.x = fmaf(a2, w.x, acc2.x); acc2.y = fmaf(a2, w.y, acc2.y);
            acc2.z = fmaf(a2, w.z, acc2.z); acc2.w = fmaf(a2, w.w, acc2.w);
            acc3.x = fmaf(a3, w.x, acc3.x); acc3.y = fmaf(a3, w.y, acc3.y);
            acc3.z = fmaf(a3, w.z, acc3.z); acc3.w = fmaf(a3, w.w, acc3.w);
        }
        __syncthreads();   // before overwriting chunk buffers
    }

    float4 accs[4] = {acc0, acc1, acc2, acc3};
    #pragma unroll
    for (int r = 0; r < 4; ++r) {
        int row = base + rb + r;
        if (row < N_NODES) {
            ushort4 o;
            o.x = f2bf(accs[r].x); o.y = f2bf(accs[r].y);
            o.z = f2bf(accs[r].z); o.w = f2bf(accs[r].w);
            *(ushort4*)&out[(size_t)row * 64 + ct] = o;
        }
    }
}

// ---------------- fused layer tail (bf16 u input), persistent, shared weight buffer ----------------
template <bool NEXT>
__global__ __launch_bounds__(256) void k_fused(const uint2* __restrict__ U2,
                                               const float* __restrict__ W2,
                                               const float* __restrict__ sums,
                                               const float* __restrict__ g_,
                                               const float* __restrict__ be,
                                               const float* __restrict__ b2,
                                               const int* __restrict__ batch,
                                               float* __restrict__ pooled, int layer,
                                               const float* __restrict__ W1n,
                                               ushort_t* __restrict__ ynext) {
    constexpr int K = 64, KP = 68, KQ = 16;
    __shared__ float Al[64 * KP];       // 17408 B
    __shared__ float Wl[K * 64];        // 16384 B (time-shared: W2 then W1n)
    __shared__ float Pl[256];
    __shared__ __align__(16) float Sc[64];
    __shared__ __align__(16) float Sh[64];
    int tid = threadIdx.x;

    if (tid < 64) {
        const float inv_n = 1.0f / N_NODES;
        float mean = sums[tid] * inv_n;
        float var = sums[64 + tid] * inv_n - mean * mean;
        if (var < 0.f) var = 0.f;
        float inv = rsqrtf(var + 1e-5f);
        float sc = inv * g_[tid];
        Sc[tid] = sc;
        Sh[tid] = be[tid] - mean * sc;
    }
    __syncthreads();

    int ct = (tid & 15) * 4;
    int rb = (tid >> 4) * 4;

    for (int tile = blockIdx.x; tile < N_TILES; tile += gridDim.x) {
        int base = tile * 64;

        // load Wl <- W2 ; build Al = relu(BN(u))
        for (int i = tid; i < K * 16; i += 256)
            ((float4*)Wl)[i] = ((const float4*)W2)[i];
        {
            bool full = (base + 64 <= N_NODES);
            for (int i = tid; i < 16 * K; i += 256) {
                int row = i / KQ, kq = i % KQ, kk = kq * 4;
                int grow = base + row;
                if (!full && grow >= N_NODES) grow = N_NODES - 1;
                uint2 w = U2[(size_t)grow * 16 + kq];
                float4 v = {lo_bf(w.x), hi_bf(w.x), lo_bf(w.y), hi_bf(w.y)};
                float4 sc = *(const float4*)&Sc[kk];
                float4 sh = *(const float4*)&Sh[kk];
                v.x = fmaxf(fmaf(v.x, sc.x, sh.x), 0.f);
                v.y = fmaxf(fmaf(v.y, sc.y, sh.y), 0.f);
                v.z = fmaxf(fmaf(v.z, sc.z, sh.z), 0.f);
                v.w = fmaxf(fmaf(v.w, sc.w, sh.w), 0.f);
                *(float4*)&Al[row * KP + kk] = v;
            }
        }
        __syncthreads();

        // GEMM1: h = Al(u) @ Wl(W2)
        float4 acc0 = {0.f, 0.f, 0.f, 0.f}, acc1 = acc0, acc2 = acc0, acc3 = acc0;
        {
            const float* A0 = &Al[(rb + 0) * KP];
            const float* A1 = &Al[(rb + 1) * KP];
            const float* A2 = &Al[(rb + 2) * KP];
            const float* A3 = &Al[(rb + 3) * KP];
            #pragma unroll 4
            for (int k = 0; k < K; ++k) {
                float4 w = *(const float4*)&Wl[k * 64 + ct];
                float a0 = A0[k], a1 = A1[k], a2 = A2[k], a3 = A3[k];
                acc0.x = fmaf(a0, w.x, acc0.x); acc0.y = fmaf(a0, w.y, acc0.y);
                acc0.z = fmaf(a0, w.z, acc0.z); acc0.w = fmaf(a0, w.w, acc0.w);
                acc1.x = fmaf(a1, w.x, acc1.x); acc1.y = fmaf(a1, w.y, acc1.y);
                acc1.z = fmaf(a1, w.z, acc1.z); acc1.w = fmaf(a1, w.w, acc1.w);
                acc2.x = fmaf(a2, w.x, acc2.x); acc2.y = fmaf(a2, w.y, acc2.y);
                acc2.z = fmaf(a2, w.z, acc2.z); acc2.w = fmaf(a2, w.w, acc2.w);
                acc3.x = fmaf(a3, w.x, acc3.x); acc3.y = fmaf(a3, w.y, acc3.y);
                acc3.z = fmaf(a3, w.z, acc3.z); acc3.w = fmaf(a3, w.w, acc3.w);
            }
        }
        __syncthreads();   // done reading Al(u) and Wl(W2)

        // write h into Al; load Wl <- W1n (different buffers, both writes)
        {
            float4 bb = *(const float4*)&b2[ct];
            float4 accs[4] = {acc0, acc1, acc2, acc3};
            #pragma unroll
            for (int r = 0; r < 4; ++r) {
                float4 o;
                o.x = fmaxf(accs[r].x + bb.x, 0.f);
                o.y = fmaxf(accs[r].y + bb.y, 0.f);
                o.z = fmaxf(accs[r].z + bb.z, 0.f);
                o.w = fmaxf(accs[r].w + bb.w, 0.f);
                *(float4*)&Al[(rb + r) * KP + ct] = o;
            }
        }
        if (NEXT) {
            for (int i = tid; i < K * 16; i += 256)
                ((float4*)Wl)[i] = ((const float4*)W1n)[i];
        }
        __syncthreads();   // h tile + W1n ready

        // GEMM2 first (no internal barriers): ynext = bf16(h @ W1n)
        if (NEXT) {
            float4 y0 = {0.f, 0.f, 0.f, 0.f}, y1 = y0, y2_ = y0, y3 = y0;
            const float* A0 = &Al[(rb + 0) * KP];
            const float* A1 = &Al[(rb + 1) * KP];
            const float* A2 = &Al[(rb + 2) * KP];
            const float* A3 = &Al[(rb + 3) * KP];
            #pragma unroll 4
            for (int k = 0; k < K; ++k) {
                float4 w = *(const float4*)&Wl[k * 64 + ct];
                float a0 = A0[k], a1 = A1[k], a2 = A2[k], a3 = A3[k];
                y0.x = fmaf(a0, w.x, y0.x); y0.y = fmaf(a0, w.y, y0.y);
                y0.z = fmaf(a0, w.z, y0.z); y0.w = fmaf(a0, w.w, y0.w);
                y1.x = fmaf(a1, w.x, y1.x); y1.y = fmaf(a1, w.y, y1.y);
                y1.z = fmaf(a1, w.z, y1.z); y1.w = fmaf(a1, w.w, y1.w);
                y2_.x = fmaf(a2, w.x, y2_.x); y2_.y = fmaf(a2, w.y, y2_.y);
                y2_.z = fmaf(a2, w.z, y2_.z); y2_.w = fmaf(a2, w.w, y2_.w);
                y3.x = fmaf(a3, w.x, y3.x); y3.y = fmaf(a3, w.y, y3.y);
                y3.z = fmaf(a3, w.z, y3.z); y3.w = fmaf(a3, w.w, y3.w);
            }
            float4 ys[4] = {y0, y1, y2_, y3};
            #pragma unroll
            for (int r = 0; r < 4; ++r) {
                int row = base + rb + r;
                if (row < N_NODES) {
                    ushort4 o;
                    o.x = f2bf(ys[r].x); o.y = f2bf(ys[r].y);
                    o.z = f2bf(ys[r].z); o.w = f2bf(ys[r].w);
                    *(ushort4*)&ynext[(size_t)row * 64 + ct] = o;
                }
            }
        }

        // pooling over graph segments (batch sorted); internal barriers
        {
            int lastEx = base + 64; if (lastEx > N_NODES) lastEx = N_NODES;
            int gstart = batch[base];
            int gend = batch[lastEx - 1];
            if (gstart < 0) gstart = 0;
            if (gend > N_GRAPHS - 1) gend = N_GRAPHS - 1;
            int col = tid & 63, q = tid >> 6;
            int rs = base;
            for (int g = gstart; g <= gend; ++g) {
                int lo = rs, hi = lastEx;
                while (lo < hi) { int mid = (lo + hi) >> 1; if (batch[mid] <= g) lo = mid + 1; else hi = mid; }
                int re = lo;
                float s = 0.f;
                for (int r = rs + q; r < re; r += 4) s += Al[(r - base) * KP + col];
                Pl[tid] = s;
                __syncthreads();
                if (tid < 64) {
                    float tot = (Pl[col] + Pl[64 + col]) + (Pl[128 + col] + Pl[192 + col]);
                    atomicAdd(&pooled[g * 256 + layer * 64 + col], tot);
                }
                __syncthreads();
                rs = re;
            }
        }
        __syncthreads();   // tile end: Al/Wl safe to overwrite
    }
}

// ---------------- head ----------------
__global__ __launch_bounds__(64) void k_head1(const float* __restrict__ pooled,
                                              const float* __restrict__ W, const float* __restrict__ b,
                                              float* __restrict__ t1) {
    __shared__ __align__(16) float pl[256];
    int g = blockIdx.x, lane = threadIdx.x;
    ((float4*)pl)[lane] = ((const float4*)(pooled + g * 256))[lane];
    __syncthreads();
    float acc = b[lane];
    for (int k = 0; k < 256; ++k) acc += pl[k] * W[k * 64 + lane];
    t1[g * 64 + lane] = acc;
}

__global__ __launch_bounds__(64) void k_head3(const float* __restrict__ t1,
                                              const float* __restrict__ g_, const float* __restrict__ b_,
                                              const float* __restrict__ W2, const float* __restrict__ b2,
                                              float* __restrict__ out) {
    __shared__ float v[64];
    __shared__ float o[16];
    int g = blockIdx.x, lane = threadIdx.x;
    float s = 0.f, q = 0.f;
    for (int r = 0; r < N_GRAPHS; ++r) {
        float vv = t1[r * 64 + lane];
        s += vv; q += vv * vv;
    }
    float mean = s * (1.0f / N_GRAPHS);
    float var = q * (1.0f / N_GRAPHS) - mean * mean;
    if (var < 0.f) var = 0.f;
    float inv = rsqrtf(var + 1e-5f);
    float sc = inv * g_[lane];
    float sh = b_[lane] - mean * sc;
    float x = t1[g * 64 + lane] * sc + sh;
    v[lane] = fmaxf(x, 0.f);
    __syncthreads();
    if (lane < N_CLASSES) {
        float acc = b2[lane];
        for (int k = 0; k < 64; ++k) acc += v[k] * W2[k * N_CLASSES + lane];
        o[lane] = acc;
    }
    __syncthreads();
    if (lane < N_CLASSES) {
        float m = -1e30f;
        for (int k = 0; k < N_CLASSES; ++k) m = fmaxf(m, o[k]);
        float ssum = 0.f;
        for (int k = 0; k < N_CLASSES; ++k) ssum += expf(o[k] - m);
        out[g * N_CLASSES + lane] = o[lane] - m - logf(ssum);
    }
}

// ---------------- launch ----------------
extern "C" void kernel_launch(void* const* d_in, const int* in_sizes, int n_in,
                              void* d_out, int out_size, void* d_ws, size_t ws_size,
                              hipStream_t stream) {
    const float* x      = (const float*)d_in[0];
    const int*   ei     = (const int*)d_in[1];
    const int*   srcArr = ei;
    const int*   dstArr = ei + N_EDGES;
    const int*   batch  = (const int*)d_in[2];
    const float* eps    = (const float*)d_in[3];
    const float* W1_0   = (const float*)d_in[4];
    const float* b1_0   = (const float*)d_in[5];
    const float* g_0    = (const float*)d_in[6];
    const float* be_0   = (const float*)d_in[7];
    const float* W2_0   = (const float*)d_in[8];
    const float* b2_0   = (const float*)d_in[9];
    const float* W1_r   = (const float*)d_in[10];
    const float* b1_r   = (const float*)d_in[11];
    const float* g_r    = (const float*)d_in[12];
    const float* be_r   = (const float*)d_in[13];
    const float* W2_r   = (const float*)d_in[14];
    const float* b2_r   = (const float*)d_in[15];
    const float* lin1W  = (const float*)d_in[16];
    const float* lin1b  = (const float*)d_in[17];
    const float* bn_g   = (const float*)d_in[18];
    const float* bn_b   = (const float*)d_in[19];
    const float* lin2W  = (const float*)d_in[20];
    const float* lin2b  = (const float*)d_in[21];

    char* ws = (char*)d_ws;
    auto alloc = [&](size_t bytes) {
        char* p = ws;
        ws += (bytes + 255) & ~(size_t)255;
        return p;
    };
    int*      row_ptr = (int*)alloc(((size_t)N_NODES + 1) * 4);
    int*      col_src = (int*)alloc((size_t)N_EDGES * 4);
    int*      ebuf    = (int*)alloc((size_t)N_EDGES * 4);
    int*      partial = (int*)alloc((size_t)NBLK * NB_BUCKET * 4);
    int*      goff    = (int*)alloc((size_t)NBLK * NB_BUCKET * 4);
    int*      btotal  = (int*)alloc((size_t)NB_BUCKET * 4);
    int*      bbase   = (int*)alloc(((size_t)NB_BUCKET + 1) * 4);
    ushort_t* ybf     = (ushort_t*)alloc((size_t)N_NODES * 64 * 2);
    ushort_t* ubf     = (ushort_t*)alloc((size_t)N_NODES * 64 * 2);
    float*    statsA  = (float*)alloc(NLAYERS * 128 * 4);
    float*    pooled  = (float*)alloc((size_t)N_GRAPHS * 256 * 4);
    float*    t1      = (float*)alloc((size_t)N_GRAPHS * 64 * 4);
    // stats partials alias ebuf: ebuf dead after kb_csr; written by k_stats
    // (stream-ordered after). NSTAT*128*4 = 256 KB <= 6.4 MB. Proven-safe
    // pattern (R4 used the same alias and passed).
    float*    spart   = (float*)ebuf;

    k_zero<<<(N_GRAPHS * 256 + 255) / 256, 256, 0, stream>>>(btotal, statsA, pooled);
    kb_hist<<<NBLK, 512, 0, stream>>>(dstArr, partial, btotal);
    kb_base<<<1, 256, 0, stream>>>(btotal, bbase);
    kb_scan<<<NB_BUCKET, 256, 0, stream>>>(partial, bbase, goff);
    kb_scatter<<<NBLK, 512, 0, stream>>>(srcArr, dstArr, goff, ebuf);
    kb_csr<<<NB_BUCKET, 512, 0, stream>>>(ebuf, bbase, row_ptr, col_src);

    const int gemm_grid = (N_NODES + 63) / 64;      // 1563

    // layer 0 front GEMM: y0 = bf16(x @ W1_0)
    k_gemm1<128><<<gemm_grid, 256, 0, stream>>>(x, W1_0, ybf);

    for (int l = 0; l < NLAYERS; ++l) {
        const float *b1, *gg, *be, *W2, *b2;
        if (l == 0) { b1 = b1_0; gg = g_0; be = be_0; W2 = W2_0; b2 = b2_0; }
        else {
            b1 = b1_r + (size_t)(l - 1) * 64;
            gg = g_r  + (size_t)(l - 1) * 64;
            be = be_r + (size_t)(l - 1) * 64;
            W2 = W2_r + (size_t)(l - 1) * 64 * 64;
            b2 = b2_r + (size_t)(l - 1) * 64;
        }
        k_aggregate_u<<<NAGG, 256, 0, stream>>>((const uint2*)ybf, row_ptr, col_src, eps, l, b1,
                                                (uint2*)ubf);
        k_stats<<<NSTAT, 256, 0, stream>>>((const uint2*)ubf, spart);
        k_redstats<<<128, 256, 0, stream>>>(spart, statsA + l * 128);
        if (l < NLAYERS - 1) {
            const float* W1n = W1_r + (size_t)l * 64 * 64;
            k_fused<true><<<FUSED_GRID, 256, 0, stream>>>((const uint2*)ubf, W2, statsA + l * 128, gg, be, b2,
                                                          batch, pooled, l, W1n, ybf);
        } else {
            k_fused<false><<<FUSED_GRID, 256, 0, stream>>>((const uint2*)ubf, W2, statsA + l * 128, gg, be, b2,
                                                           batch, pooled, l, nullptr, nullptr);
        }
    }

    k_head1<<<N_GRAPHS, 64, 0, stream>>>(pooled, lin1W, lin1b, t1);
    k_head3<<<N_GRAPHS, 64, 0, stream>>>(t1, bn_g, bn_b, lin2W, lin2b, (float*)d_out);
}

// Round 7
// 509.419 us; speedup vs baseline: 1.1856x; 1.0275x over previous
//
#include <hip/hip_runtime.h>

#define N_NODES 100000
#define N_EDGES 1600000
#define F_IN 128
#define HID 64
#define NLAYERS 4
#define N_GRAPHS 512
#define N_CLASSES 10

// bucketed CSR build
#define NB_BUCKET 256
#define NODES_PER_BUCKET 391            // ceil(100000/256); 256*391 = 100096
#define NBLK 256
#define EDGES_PER_BLK (N_EDGES / NBLK)  // 6250 exactly

#define N_TILES ((N_NODES + 63) / 64)   // 1563
#define FUSED_GRID 1024                 // 4 blocks/CU x 256 CU (LDS-limited)
#define NAGG 2048                       // aggregate persistent grid
#define NSTAT 512                       // stats grid

typedef unsigned int uint_t;
typedef unsigned short ushort_t;

__device__ __forceinline__ float lo_bf(uint_t w) { return __uint_as_float(w << 16); }
__device__ __forceinline__ float hi_bf(uint_t w) { return __uint_as_float(w & 0xffff0000u); }
__device__ __forceinline__ ushort_t f2bf(float f) {
    uint_t u = __float_as_uint(f);
    u += 0x7fffu + ((u >> 16) & 1u);   // round-to-nearest-even
    return (ushort_t)(u >> 16);
}
__device__ __forceinline__ uint_t pack2(float a, float b) {
    return ((uint_t)f2bf(b) << 16) | (uint_t)f2bf(a);
}

// ---------------- workspace zeroing ----------------
__global__ __launch_bounds__(256) void k_zero(int* __restrict__ btotal,
                                              float* __restrict__ statsA,
                                              float* __restrict__ pooled) {
    int i = blockIdx.x * 256 + threadIdx.x;
    if (i < NB_BUCKET) btotal[i] = 0;
    if (i < NLAYERS * 128) statsA[i] = 0.f;
    if (i < N_GRAPHS * 256) pooled[i] = 0.f;
}

// ---------------- bucketed CSR build (no global returning atomics) ----------------
__global__ __launch_bounds__(512) void kb_hist(const int* __restrict__ dst,
                                               int* __restrict__ partial,
                                               int* __restrict__ btotal) {
    __shared__ int h[NB_BUCKET];
    int tid = threadIdx.x;
    if (tid < NB_BUCKET) h[tid] = 0;
    __syncthreads();
    int e0 = blockIdx.x * EDGES_PER_BLK;
    for (int i = tid; i < EDGES_PER_BLK; i += 512) {
        uint_t d = (uint_t)dst[e0 + i];
        if (d >= (uint_t)N_NODES) d = N_NODES - 1;
        atomicAdd(&h[d / NODES_PER_BUCKET], 1);
    }
    __syncthreads();
    if (tid < NB_BUCKET) {
        int c = h[tid];
        partial[blockIdx.x * NB_BUCKET + tid] = c;
        if (c) atomicAdd(&btotal[tid], c);   // non-returning, 65K total
    }
}

__global__ __launch_bounds__(256) void kb_base(const int* __restrict__ btotal,
                                               int* __restrict__ bbase) {
    __shared__ int sh[NB_BUCKET];
    int tid = threadIdx.x;
    sh[tid] = btotal[tid];
    __syncthreads();
    for (int off = 1; off < NB_BUCKET; off <<= 1) {
        int t = (tid >= off) ? sh[tid - off] : 0;
        __syncthreads();
        sh[tid] += t;
        __syncthreads();
    }
    bbase[tid + 1] = sh[tid];
    if (tid == 0) bbase[0] = 0;
}

__global__ __launch_bounds__(256) void kb_scan(const int* __restrict__ partial,
                                               const int* __restrict__ bbase,
                                               int* __restrict__ goff) {
    __shared__ int sh[NBLK];
    int b = blockIdx.x, tid = threadIdx.x;
    sh[tid] = partial[tid * NB_BUCKET + b];
    __syncthreads();
    for (int off = 1; off < NBLK; off <<= 1) {
        int t = (tid >= off) ? sh[tid - off] : 0;
        __syncthreads();
        sh[tid] += t;
        __syncthreads();
    }
    int excl = (tid == 0) ? 0 : sh[tid - 1];
    goff[tid * NB_BUCKET + b] = bbase[b] + excl;
}

__global__ __launch_bounds__(512) void kb_scatter(const int* __restrict__ src,
                                                  const int* __restrict__ dst,
                                                  const int* __restrict__ goff,
                                                  int* __restrict__ ebuf) {
    __shared__ int cur[NB_BUCKET];
    int tid = threadIdx.x;
    if (tid < NB_BUCKET) cur[tid] = goff[blockIdx.x * NB_BUCKET + tid];
    __syncthreads();
    int e0 = blockIdx.x * EDGES_PER_BLK;
    for (int i = tid; i < EDGES_PER_BLK; i += 512) {
        uint_t d = (uint_t)dst[e0 + i];
        if (d >= (uint_t)N_NODES) d = N_NODES - 1;
        uint_t s = (uint_t)src[e0 + i];
        if (s >= (uint_t)N_NODES) s = 0;
        int b = (int)(d / NODES_PER_BUCKET);
        int dl = (int)d - b * NODES_PER_BUCKET;     // < 391, 9 bits
        int pos = atomicAdd(&cur[b], 1);            // LDS returning atomic
        ebuf[pos] = (dl << 17) | (int)s;            // src < 2^17
    }
}

__global__ __launch_bounds__(512) void kb_csr(const int* __restrict__ ebuf,
                                              const int* __restrict__ bbase,
                                              int* __restrict__ row_ptr,
                                              int* __restrict__ col_src) {
    __shared__ int cnt[512];
    __shared__ int sh[512];
    __shared__ int off[512];
    int tid = threadIdx.x, b = blockIdx.x;
    int s0 = bbase[b], s1 = bbase[b + 1];
    int n = s1 - s0;
    cnt[tid] = 0;
    __syncthreads();
    for (int i = tid; i < n; i += 512) {
        int dl = ebuf[s0 + i] >> 17;
        atomicAdd(&cnt[dl], 1);
    }
    __syncthreads();
    sh[tid] = cnt[tid];
    __syncthreads();
    for (int o = 1; o < 512; o <<= 1) {
        int t = (tid >= o) ? sh[tid - o] : 0;
        __syncthreads();
        sh[tid] += t;
        __syncthreads();
    }
    off[tid] = (tid == 0) ? 0 : sh[tid - 1];
    cnt[tid] = 0;

    int node0 = b * NODES_PER_BUCKET;
    int ncnt = N_NODES - node0;
    if (ncnt > NODES_PER_BUCKET) ncnt = NODES_PER_BUCKET;
    if (tid < ncnt) row_ptr[node0 + tid] = s0 + off[tid];
    if (b == NB_BUCKET - 1 && tid == 0) row_ptr[N_NODES] = N_EDGES;
    __syncthreads();

    for (int i = tid; i < n; i += 512) {
        int v = ebuf[s0 + i];
        int dl = v >> 17;
        int r = atomicAdd(&cnt[dl], 1);             // LDS returning atomic
        col_src[s0 + off[dl] + r] = v & 0x1FFFF;
    }
}

// ---------------- aggregation on bf16 y (dim 64) -> bf16 u (R2-proven version) ----------------
__global__ __launch_bounds__(256) void k_aggregate_u(const uint2* __restrict__ y2,
                                                     const int* __restrict__ row_ptr,
                                                     const int* __restrict__ col_src,
                                                     const float* __restrict__ eps, int layer,
                                                     const float* __restrict__ b1,
                                                     uint2* __restrict__ u2) {
    int wid = threadIdx.x >> 6, lane = threadIdx.x & 63;
    int gid = lane >> 4, l4 = lane & 15;
    float one_eps = 1.0f + eps[layer];
    int stride = gridDim.x * 4;

    for (int node = blockIdx.x * 4 + wid; node < N_NODES; node += stride) {
        int e0 = row_ptr[node], e1 = row_ptr[node + 1];
        if (e0 < 0) e0 = 0;
        if (e1 > N_EDGES) e1 = N_EDGES;
        if (e1 < e0) e1 = e0;

        float4 a0 = {0.f, 0.f, 0.f, 0.f}, a1 = a0, a2 = a0, a3 = a0;

        for (int ebase = e0; ebase < e1; ebase += 64) {
            int len = e1 - ebase; if (len > 64) len = 64;
            // one coalesced load of up to 64 edge sources (clamped; e1 >= 1 here)
            int ci = ebase + lane; if (ci > e1 - 1) ci = e1 - 1;
            int sv = col_src[ci];
            sv = (int)min((uint_t)sv, (uint_t)(N_NODES - 1));

            int nfull = len >> 2;   // steps of 4 edges
            int rem = len & 3;
            int j = 0;
            for (; j + 4 <= nfull; j += 4) {
                int s0 = __shfl(sv, (j + 0) * 4 + gid, 64);
                int s1 = __shfl(sv, (j + 1) * 4 + gid, 64);
                int s2 = __shfl(sv, (j + 2) * 4 + gid, 64);
                int s3 = __shfl(sv, (j + 3) * 4 + gid, 64);
                uint2 w0 = y2[(size_t)s0 * 16 + l4];
                uint2 w1 = y2[(size_t)s1 * 16 + l4];
                uint2 w2 = y2[(size_t)s2 * 16 + l4];
                uint2 w3 = y2[(size_t)s3 * 16 + l4];
                a0.x += lo_bf(w0.x); a0.y += hi_bf(w0.x); a0.z += lo_bf(w0.y); a0.w += hi_bf(w0.y);
                a1.x += lo_bf(w1.x); a1.y += hi_bf(w1.x); a1.z += lo_bf(w1.y); a1.w += hi_bf(w1.y);
                a2.x += lo_bf(w2.x); a2.y += hi_bf(w2.x); a2.z += lo_bf(w2.y); a2.w += hi_bf(w2.y);
                a3.x += lo_bf(w3.x); a3.y += hi_bf(w3.x); a3.z += lo_bf(w3.y); a3.w += hi_bf(w3.y);
            }
            for (; j < nfull; ++j) {
                int s = __shfl(sv, j * 4 + gid, 64);
                uint2 w = y2[(size_t)s * 16 + l4];
                a0.x += lo_bf(w.x); a0.y += hi_bf(w.x); a0.z += lo_bf(w.y); a0.w += hi_bf(w.y);
            }
            if (rem) {
                int s = __shfl(sv, nfull * 4 + gid, 64);
                if (gid < rem) {
                    uint2 w = y2[(size_t)s * 16 + l4];
                    a1.x += lo_bf(w.x); a1.y += hi_bf(w.x); a1.z += lo_bf(w.y); a1.w += hi_bf(w.y);
                }
            }
        }

        float4 t;
        t.x = (a0.x + a1.x) + (a2.x + a3.x);
        t.y = (a0.y + a1.y) + (a2.y + a3.y);
        t.z = (a0.z + a1.z) + (a2.z + a3.z);
        t.w = (a0.w + a1.w) + (a2.w + a3.w);
        t.x += __shfl_xor(t.x, 16, 64); t.x += __shfl_xor(t.x, 32, 64);
        t.y += __shfl_xor(t.y, 16, 64); t.y += __shfl_xor(t.y, 32, 64);
        t.z += __shfl_xor(t.z, 16, 64); t.z += __shfl_xor(t.z, 32, 64);
        t.w += __shfl_xor(t.w, 16, 64); t.w += __shfl_xor(t.w, 32, 64);

        if (gid == 0) {
            uint2 ws = y2[(size_t)node * 16 + l4];
            float4 bb = *(const float4*)&b1[4 * l4];
            float ox = t.x + one_eps * lo_bf(ws.x) + bb.x;
            float oy = t.y + one_eps * hi_bf(ws.x) + bb.y;
            float oz = t.z + one_eps * lo_bf(ws.y) + bb.z;
            float ow = t.w + one_eps * hi_bf(ws.y) + bb.w;
            uint2 o2;
            o2.x = pack2(ox, oy);
            o2.y = pack2(oz, ow);
            u2[(size_t)node * 16 + l4] = o2;
        }
    }
}

// ---------------- column stats over bf16 u [N_NODES x 64], atomic-free two-stage ----------------
__global__ __launch_bounds__(256) void k_stats(const uint2* __restrict__ u2,
                                               float* __restrict__ partials) {
    __shared__ float sh[256 * 8];
    int tid = threadIdx.x;
    float a[4] = {0.f, 0.f, 0.f, 0.f}, b[4] = {0.f, 0.f, 0.f, 0.f};
    for (size_t i = (size_t)blockIdx.x * 256 + tid; i < (size_t)N_NODES * 16; i += (size_t)gridDim.x * 256) {
        uint2 w = u2[i];
        float v0 = lo_bf(w.x), v1 = hi_bf(w.x), v2 = lo_bf(w.y), v3 = hi_bf(w.y);
        a[0] += v0; b[0] += v0 * v0;
        a[1] += v1; b[1] += v1 * v1;
        a[2] += v2; b[2] += v2 * v2;
        a[3] += v3; b[3] += v3 * v3;
    }
    #pragma unroll
    for (int j = 0; j < 4; ++j) { sh[tid * 8 + j] = a[j]; sh[tid * 8 + 4 + j] = b[j]; }
    __syncthreads();
    if (tid < 64) {
        int quad = tid >> 2, o = tid & 3;
        float s = 0.f, ss = 0.f;
        for (int g = 0; g < 16; ++g) {
            int t = g * 16 + quad;
            s  += sh[t * 8 + o];
            ss += sh[t * 8 + 4 + o];
        }
        partials[(size_t)blockIdx.x * 128 + tid]      = s;
        partials[(size_t)blockIdx.x * 128 + 64 + tid] = ss;
    }
}

__global__ __launch_bounds__(256) void k_redstats(const float* __restrict__ partials,
                                                  float* __restrict__ outp) {
    __shared__ float sh[256];
    int b = blockIdx.x, tid = threadIdx.x;
    float v = 0.f;
    for (int i = tid; i < NSTAT; i += 256) v += partials[(size_t)i * 128 + b];
    sh[tid] = v;
    __syncthreads();
    for (int off = 128; off > 0; off >>= 1) {
        if (tid < off) sh[tid] += sh[tid + off];
        __syncthreads();
    }
    if (tid == 0) outp[b] = sh[0];
}

// ---------------- GEMM1 (layer 0 only): ybf = bf16(x @ W1_0), K-chunked for occupancy ----------------
template <int K>
__global__ __launch_bounds__(256) void k_gemm1(const float* __restrict__ A,
                                               const float* __restrict__ W,
                                               ushort_t* __restrict__ out) {
    constexpr int KC = 64;            // K-chunk
    constexpr int KP = KC + 4;        // padded
    __shared__ float Al[64 * KP];     // 17408 B
    __shared__ float Wl[KC * 64];     // 16384 B  -> ~34 KB total, 4 blocks/CU
    int tid = threadIdx.x;
    int base = blockIdx.x * 64;
    int ct = (tid & 15) * 4;
    int rb = (tid >> 4) * 4;
    float4 acc0 = {0.f, 0.f, 0.f, 0.f}, acc1 = acc0, acc2 = acc0, acc3 = acc0;
    bool full = (base + 64 <= N_NODES);

    #pragma unroll
    for (int kc = 0; kc < K; kc += KC) {
        for (int i = tid; i < KC * 16; i += 256)
            ((float4*)Wl)[i] = ((const float4*)(W + (size_t)kc * 64))[i];
        for (int i = tid; i < 64 * (KC / 4); i += 256) {
            int row = i / (KC / 4), kq = i % (KC / 4);
            int grow = base + row;
            if (!full && grow >= N_NODES) grow = N_NODES - 1;
            float4 v = ((const float4*)(A + (size_t)grow * K + kc))[kq];
            *(float4*)&Al[row * KP + kq * 4] = v;
        }
        __syncthreads();

        const float* A0 = &Al[(rb + 0) * KP];
        const float* A1 = &Al[(rb + 1) * KP];
        const float* A2 = &Al[(rb + 2) * KP];
        const float* A3 = &Al[(rb + 3) * KP];
        #pragma unroll 4
        for (int k = 0; k < KC; ++k) {
            float4 w = *(const float4*)&Wl[k * 64 + ct];
            float a0 = A0[k], a1 = A1[k], a2 = A2[k], a3 = A3[k];
            acc0.x = fmaf(a0, w.x, acc0.x); acc0.y = fmaf(a0, w.y, acc0.y);
            acc0.z = fmaf(a0, w.z, acc0.z); acc0.w = fmaf(a0, w.w, acc0.w);
            acc1.x = fmaf(a1, w.x, acc1.x); acc1.y = fmaf(a1, w.y, acc1.y);
            acc1.z = fmaf(a1, w.z, acc1.z); acc1.w = fmaf(a1, w.w, acc1.w);
            acc2.x = fmaf(a2, w.x, acc2.x); acc2.y = fmaf(a2, w.y, acc2.y);
            acc2.z = fmaf(a2, w.z, acc2.z); acc2.w = fmaf(a2, w.w, acc2.w);
            acc3.x = fmaf(a3, w.x, acc3.x); acc3.y = fmaf(a3, w.y, acc3.y);
            acc3.z = fmaf(a3, w.z, acc3.z); acc3.w = fmaf(a3, w.w, acc3.w);
        }
        __syncthreads();   // before overwriting chunk buffers
    }

    float4 accs[4] = {acc0, acc1, acc2, acc3};
    #pragma unroll
    for (int r = 0; r < 4; ++r) {
        int row = base + rb + r;
        if (row < N_NODES) {
            ushort4 o;
            o.x = f2bf(accs[r].x); o.y = f2bf(accs[r].y);
            o.z = f2bf(accs[r].z); o.w = f2bf(accs[r].w);
            *(ushort4*)&out[(size_t)row * 64 + ct] = o;
        }
    }
}

// ---------------- fused layer tail (bf16 u input), persistent, shared weight buffer,
// ---------------- + T14 register prefetch of next tile's u ----------------
template <bool NEXT>
__global__ __launch_bounds__(256) void k_fused(const uint2* __restrict__ U2,
                                               const float* __restrict__ W2,
                                               const float* __restrict__ sums,
                                               const float* __restrict__ g_,
                                               const float* __restrict__ be,
                                               const float* __restrict__ b2,
                                               const int* __restrict__ batch,
                                               float* __restrict__ pooled, int layer,
                                               const float* __restrict__ W1n,
                                               ushort_t* __restrict__ ynext) {
    constexpr int K = 64, KP = 68;
    __shared__ float Al[64 * KP];       // 17408 B
    __shared__ float Wl[K * 64];        // 16384 B (time-shared: W2 then W1n)
    __shared__ float Pl[256];
    __shared__ __align__(16) float Sc[64];
    __shared__ __align__(16) float Sh[64];
    int tid = threadIdx.x;

    if (tid < 64) {
        const float inv_n = 1.0f / N_NODES;
        float mean = sums[tid] * inv_n;
        float var = sums[64 + tid] * inv_n - mean * mean;
        if (var < 0.f) var = 0.f;
        float inv = rsqrtf(var + 1e-5f);
        float sc = inv * g_[tid];
        Sc[tid] = sc;
        Sh[tid] = be[tid] - mean * sc;
    }
    __syncthreads();

    int ct = (tid & 15) * 4;
    int rb = (tid >> 4) * 4;
    // u-prefetch mapping: thread handles rows {r0+16j, j=0..3} at column-quad q0
    int r0 = tid >> 4, q0 = tid & 15;
    float4 scv = *(const float4*)&Sc[q0 * 4];
    float4 shv = *(const float4*)&Sh[q0 * 4];

    uint2 up0, up1, up2, up3;   // prefetched u (named regs, static indexing)

    // prologue: load u for first tile
    {
        int base = blockIdx.x * 64;
        int g0 = base + r0, g1 = base + r0 + 16, g2 = base + r0 + 32, g3 = base + r0 + 48;
        if (g0 > N_NODES - 1) g0 = N_NODES - 1;
        if (g1 > N_NODES - 1) g1 = N_NODES - 1;
        if (g2 > N_NODES - 1) g2 = N_NODES - 1;
        if (g3 > N_NODES - 1) g3 = N_NODES - 1;
        up0 = U2[(size_t)g0 * 16 + q0];
        up1 = U2[(size_t)g1 * 16 + q0];
        up2 = U2[(size_t)g2 * 16 + q0];
        up3 = U2[(size_t)g3 * 16 + q0];
    }

    for (int tile = blockIdx.x; tile < N_TILES; tile += gridDim.x) {
        int base = tile * 64;

        // load Wl <- W2 ; build Al = relu(BN(u)) from prefetched regs
        for (int i = tid; i < K * 16; i += 256)
            ((float4*)Wl)[i] = ((const float4*)W2)[i];
        {
            #define UNPK(UR, RR) { \
                float4 v = {lo_bf((UR).x), hi_bf((UR).x), lo_bf((UR).y), hi_bf((UR).y)}; \
                v.x = fmaxf(fmaf(v.x, scv.x, shv.x), 0.f); \
                v.y = fmaxf(fmaf(v.y, scv.y, shv.y), 0.f); \
                v.z = fmaxf(fmaf(v.z, scv.z, shv.z), 0.f); \
                v.w = fmaxf(fmaf(v.w, scv.w, shv.w), 0.f); \
                *(float4*)&Al[(RR) * KP + q0 * 4] = v; }
            UNPK(up0, r0);
            UNPK(up1, r0 + 16);
            UNPK(up2, r0 + 32);
            UNPK(up3, r0 + 48);
            #undef UNPK
        }
        __syncthreads();

        // GEMM1: h = Al(u) @ Wl(W2)
        float4 acc0 = {0.f, 0.f, 0.f, 0.f}, acc1 = acc0, acc2 = acc0, acc3 = acc0;
        {
            const float* A0 = &Al[(rb + 0) * KP];
            const float* A1 = &Al[(rb + 1) * KP];
            const float* A2 = &Al[(rb + 2) * KP];
            const float* A3 = &Al[(rb + 3) * KP];
            #pragma unroll 4
            for (int k = 0; k < K; ++k) {
                float4 w = *(const float4*)&Wl[k * 64 + ct];
                float a0 = A0[k], a1 = A1[k], a2 = A2[k], a3 = A3[k];
                acc0.x = fmaf(a0, w.x, acc0.x); acc0.y = fmaf(a0, w.y, acc0.y);
                acc0.z = fmaf(a0, w.z, acc0.z); acc0.w = fmaf(a0, w.w, acc0.w);
                acc1.x = fmaf(a1, w.x, acc1.x); acc1.y = fmaf(a1, w.y, acc1.y);
                acc1.z = fmaf(a1, w.z, acc1.z); acc1.w = fmaf(a1, w.w, acc1.w);
                acc2.x = fmaf(a2, w.x, acc2.x); acc2.y = fmaf(a2, w.y, acc2.y);
                acc2.z = fmaf(a2, w.z, acc2.z); acc2.w = fmaf(a2, w.w, acc2.w);
                acc3.x = fmaf(a3, w.x, acc3.x); acc3.y = fmaf(a3, w.y, acc3.y);
                acc3.z = fmaf(a3, w.z, acc3.z); acc3.w = fmaf(a3, w.w, acc3.w);
            }
        }
        __syncthreads();   // done reading Al(u) and Wl(W2)

        // write h into Al; load Wl <- W1n (different buffers, both writes)
        {
            float4 bb = *(const float4*)&b2[ct];
            float4 accs[4] = {acc0, acc1, acc2, acc3};
            #pragma unroll
            for (int r = 0; r < 4; ++r) {
                float4 o;
                o.x = fmaxf(accs[r].x + bb.x, 0.f);
                o.y = fmaxf(accs[r].y + bb.y, 0.f);
                o.z = fmaxf(accs[r].z + bb.z, 0.f);
                o.w = fmaxf(accs[r].w + bb.w, 0.f);
                *(float4*)&Al[(rb + r) * KP + ct] = o;
            }
        }
        if (NEXT) {
            for (int i = tid; i < K * 16; i += 256)
                ((float4*)Wl)[i] = ((const float4*)W1n)[i];
        }
        __syncthreads();   // h tile + W1n ready

        // GEMM2 (no internal barriers): ynext = bf16(h @ W1n)
        if (NEXT) {
            float4 y0 = {0.f, 0.f, 0.f, 0.f}, y1 = y0, y2_ = y0, y3 = y0;
            const float* A0 = &Al[(rb + 0) * KP];
            const float* A1 = &Al[(rb + 1) * KP];
            const float* A2 = &Al[(rb + 2) * KP];
            const float* A3 = &Al[(rb + 3) * KP];
            #pragma unroll 4
            for (int k = 0; k < K; ++k) {
                float4 w = *(const float4*)&Wl[k * 64 + ct];
                float a0 = A0[k], a1 = A1[k], a2 = A2[k], a3 = A3[k];
                y0.x = fmaf(a0, w.x, y0.x); y0.y = fmaf(a0, w.y, y0.y);
                y0.z = fmaf(a0, w.z, y0.z); y0.w = fmaf(a0, w.w, y0.w);
                y1.x = fmaf(a1, w.x, y1.x); y1.y = fmaf(a1, w.y, y1.y);
                y1.z = fmaf(a1, w.z, y1.z); y1.w = fmaf(a1, w.w, y1.w);
                y2_.x = fmaf(a2, w.x, y2_.x); y2_.y = fmaf(a2, w.y, y2_.y);
                y2_.z = fmaf(a2, w.z, y2_.z); y2_.w = fmaf(a2, w.w, y2_.w);
                y3.x = fmaf(a3, w.x, y3.x); y3.y = fmaf(a3, w.y, y3.y);
                y3.z = fmaf(a3, w.z, y3.z); y3.w = fmaf(a3, w.w, y3.w);
            }
            float4 ys[4] = {y0, y1, y2_, y3};
            #pragma unroll
            for (int r = 0; r < 4; ++r) {
                int row = base + rb + r;
                if (row < N_NODES) {
                    ushort4 o;
                    o.x = f2bf(ys[r].x); o.y = f2bf(ys[r].y);
                    o.z = f2bf(ys[r].z); o.w = f2bf(ys[r].w);
                    *(ushort4*)&ynext[(size_t)row * 64 + ct] = o;
                }
            }
        }

        // T14: issue next tile's u-loads now; HBM latency hides under pooling
        {
            int nt = tile + gridDim.x;
            if (nt < N_TILES) {
                int nb = nt * 64;
                int g0 = nb + r0, g1 = nb + r0 + 16, g2 = nb + r0 + 32, g3 = nb + r0 + 48;
                if (g0 > N_NODES - 1) g0 = N_NODES - 1;
                if (g1 > N_NODES - 1) g1 = N_NODES - 1;
                if (g2 > N_NODES - 1) g2 = N_NODES - 1;
                if (g3 > N_NODES - 1) g3 = N_NODES - 1;
                up0 = U2[(size_t)g0 * 16 + q0];
                up1 = U2[(size_t)g1 * 16 + q0];
                up2 = U2[(size_t)g2 * 16 + q0];
                up3 = U2[(size_t)g3 * 16 + q0];
            }
        }

        // pooling over graph segments (batch sorted); internal barriers
        {
            int lastEx = base + 64; if (lastEx > N_NODES) lastEx = N_NODES;
            int gstart = batch[base];
            int gend = batch[lastEx - 1];
            if (gstart < 0) gstart = 0;
            if (gend > N_GRAPHS - 1) gend = N_GRAPHS - 1;
            int col = tid & 63, q = tid >> 6;
            int rs = base;
            for (int g = gstart; g <= gend; ++g) {
                int lo = rs, hi = lastEx;
                while (lo < hi) { int mid = (lo + hi) >> 1; if (batch[mid] <= g) lo = mid + 1; else hi = mid; }
                int re = lo;
                float s = 0.f;
                for (int r = rs + q; r < re; r += 4) s += Al[(r - base) * KP + col];
                Pl[tid] = s;
                __syncthreads();
                if (tid < 64) {
                    float tot = (Pl[col] + Pl[64 + col]) + (Pl[128 + col] + Pl[192 + col]);
                    atomicAdd(&pooled[g * 256 + layer * 64 + col], tot);
                }
                __syncthreads();
                rs = re;
            }
        }
        __syncthreads();   // tile end: Al/Wl safe to overwrite
    }
}

// ---------------- head ----------------
__global__ __launch_bounds__(64) void k_head1(const float* __restrict__ pooled,
                                              const float* __restrict__ W, const float* __restrict__ b,
                                              float* __restrict__ t1) {
    __shared__ __align__(16) float pl[256];
    int g = blockIdx.x, lane = threadIdx.x;
    ((float4*)pl)[lane] = ((const float4*)(pooled + g * 256))[lane];
    __syncthreads();
    float acc = b[lane];
    for (int k = 0; k < 256; ++k) acc += pl[k] * W[k * 64 + lane];
    t1[g * 64 + lane] = acc;
}

__global__ __launch_bounds__(64) void k_head3(const float* __restrict__ t1,
                                              const float* __restrict__ g_, const float* __restrict__ b_,
                                              const float* __restrict__ W2, const float* __restrict__ b2,
                                              float* __restrict__ out) {
    __shared__ float v[64];
    __shared__ float o[16];
    int g = blockIdx.x, lane = threadIdx.x;
    float s = 0.f, q = 0.f;
    for (int r = 0; r < N_GRAPHS; ++r) {
        float vv = t1[r * 64 + lane];
        s += vv; q += vv * vv;
    }
    float mean = s * (1.0f / N_GRAPHS);
    float var = q * (1.0f / N_GRAPHS) - mean * mean;
    if (var < 0.f) var = 0.f;
    float inv = rsqrtf(var + 1e-5f);
    float sc = inv * g_[lane];
    float sh = b_[lane] - mean * sc;
    float x = t1[g * 64 + lane] * sc + sh;
    v[lane] = fmaxf(x, 0.f);
    __syncthreads();
    if (lane < N_CLASSES) {
        float acc = b2[lane];
        for (int k = 0; k < 64; ++k) acc += v[k] * W2[k * N_CLASSES + lane];
        o[lane] = acc;
    }
    __syncthreads();
    if (lane < N_CLASSES) {
        float m = -1e30f;
        for (int k = 0; k < N_CLASSES; ++k) m = fmaxf(m, o[k]);
        float ssum = 0.f;
        for (int k = 0; k < N_CLASSES; ++k) ssum += expf(o[k] - m);
        out[g * N_CLASSES + lane] = o[lane] - m - logf(ssum);
    }
}

// ---------------- launch ----------------
extern "C" void kernel_launch(void* const* d_in, const int* in_sizes, int n_in,
                              void* d_out, int out_size, void* d_ws, size_t ws_size,
                              hipStream_t stream) {
    const float* x      = (const float*)d_in[0];
    const int*   ei     = (const int*)d_in[1];
    const int*   srcArr = ei;
    const int*   dstArr = ei + N_EDGES;
    const int*   batch  = (const int*)d_in[2];
    const float* eps    = (const float*)d_in[3];
    const float* W1_0   = (const float*)d_in[4];
    const float* b1_0   = (const float*)d_in[5];
    const float* g_0    = (const float*)d_in[6];
    const float* be_0   = (const float*)d_in[7];
    const float* W2_0   = (const float*)d_in[8];
    const float* b2_0   = (const float*)d_in[9];
    const float* W1_r   = (const float*)d_in[10];
    const float* b1_r   = (const float*)d_in[11];
    const float* g_r    = (const float*)d_in[12];
    const float* be_r   = (const float*)d_in[13];
    const float* W2_r   = (const float*)d_in[14];
    const float* b2_r   = (const float*)d_in[15];
    const float* lin1W  = (const float*)d_in[16];
    const float* lin1b  = (const float*)d_in[17];
    const float* bn_g   = (const float*)d_in[18];
    const float* bn_b   = (const float*)d_in[19];
    const float* lin2W  = (const float*)d_in[20];
    const float* lin2b  = (const float*)d_in[21];

    char* ws = (char*)d_ws;
    auto alloc = [&](size_t bytes) {
        char* p = ws;
        ws += (bytes + 255) & ~(size_t)255;
        return p;
    };
    int*      row_ptr = (int*)alloc(((size_t)N_NODES + 1) * 4);
    int*      col_src = (int*)alloc((size_t)N_EDGES * 4);
    int*      ebuf    = (int*)alloc((size_t)N_EDGES * 4);
    int*      partial = (int*)alloc((size_t)NBLK * NB_BUCKET * 4);
    int*      goff    = (int*)alloc((size_t)NBLK * NB_BUCKET * 4);
    int*      btotal  = (int*)alloc((size_t)NB_BUCKET * 4);
    int*      bbase   = (int*)alloc(((size_t)NB_BUCKET + 1) * 4);
    ushort_t* ybf     = (ushort_t*)alloc((size_t)N_NODES * 64 * 2);
    ushort_t* ubf     = (ushort_t*)alloc((size_t)N_NODES * 64 * 2);
    float*    statsA  = (float*)alloc(NLAYERS * 128 * 4);
    float*    pooled  = (float*)alloc((size_t)N_GRAPHS * 256 * 4);
    float*    t1      = (float*)alloc((size_t)N_GRAPHS * 64 * 4);
    // stats partials alias ebuf (dead after kb_csr); proven-safe pattern.
    float*    spart   = (float*)ebuf;

    k_zero<<<(N_GRAPHS * 256 + 255) / 256, 256, 0, stream>>>(btotal, statsA, pooled);
    kb_hist<<<NBLK, 512, 0, stream>>>(dstArr, partial, btotal);
    kb_base<<<1, 256, 0, stream>>>(btotal, bbase);
    kb_scan<<<NB_BUCKET, 256, 0, stream>>>(partial, bbase, goff);
    kb_scatter<<<NBLK, 512, 0, stream>>>(srcArr, dstArr, goff, ebuf);
    kb_csr<<<NB_BUCKET, 512, 0, stream>>>(ebuf, bbase, row_ptr, col_src);

    const int gemm_grid = (N_NODES + 63) / 64;      // 1563

    // layer 0 front GEMM: y0 = bf16(x @ W1_0)
    k_gemm1<128><<<gemm_grid, 256, 0, stream>>>(x, W1_0, ybf);

    for (int l = 0; l < NLAYERS; ++l) {
        const float *b1, *gg, *be, *W2, *b2;
        if (l == 0) { b1 = b1_0; gg = g_0; be = be_0; W2 = W2_0; b2 = b2_0; }
        else {
            b1 = b1_r + (size_t)(l - 1) * 64;
            gg = g_r  + (size_t)(l - 1) * 64;
            be = be_r + (size_t)(l - 1) * 64;
            W2 = W2_r + (size_t)(l - 1) * 64 * 64;
            b2 = b2_r + (size_t)(l - 1) * 64;
        }
        k_aggregate_u<<<NAGG, 256, 0, stream>>>((const uint2*)ybf, row_ptr, col_src, eps, l, b1,
                                                (uint2*)ubf);
        k_stats<<<NSTAT, 256, 0, stream>>>((const uint2*)ubf, spart);
        k_redstats<<<128, 256, 0, stream>>>(spart, statsA + l * 128);
        if (l < NLAYERS - 1) {
            const float* W1n = W1_r + (size_t)l * 64 * 64;
            k_fused<true><<<FUSED_GRID, 256, 0, stream>>>((const uint2*)ubf, W2, statsA + l * 128, gg, be, b2,
                                                          batch, pooled, l, W1n, ybf);
        } else {
            k_fused<false><<<FUSED_GRID, 256, 0, stream>>>((const uint2*)ubf, W2, statsA + l * 128, gg, be, b2,
                                                           batch, pooled, l, nullptr, nullptr);
        }
    }

    k_head1<<<N_GRAPHS, 64, 0, stream>>>(pooled, lin1W, lin1b, t1);
    k_head3<<<N_GRAPHS, 64, 0, stream>>>(t1, bn_g, bn_b, lin2W, lin2b, (float*)d_out);
}